// Round 4
// baseline (4793.745 us; speedup 1.0000x reference)
//
#include <hip/hip_runtime.h>
#include <cstdint>
#include <cstddef>

#define BB   128
#define IN   1024
#define HID  4096
#define OUTN 1024
#define TSTEPS 100
#define KC   384   // OpenBLAS SGEMM_DEFAULT_Q — panel structure must be preserved exactly

// ---------------- tiled transpose: dst[c*R + r] = src[r*C + c] ----------------
__global__ __launch_bounds__(256) void ttrans_k(const float* __restrict__ src,
                                                float* __restrict__ dst,
                                                int R, int C) {
  __shared__ float tile[32][33];
  int tx = threadIdx.x & 31;
  int ty = threadIdx.x >> 5;            // 0..7
  int c0 = blockIdx.x * 32, r0 = blockIdx.y * 32;
  #pragma unroll
  for (int j = 0; j < 32; j += 8)
    tile[ty + j][tx] = src[(size_t)(r0 + ty + j) * C + (c0 + tx)];
  __syncthreads();
  #pragma unroll
  for (int j = 0; j < 32; j += 8)
    dst[(size_t)(c0 + ty + j) * R + (r0 + tx)] = tile[tx][ty + j];
}

// f32 LIF exactly mirroring the reference op order (no FMA contraction).
__device__ __forceinline__ unsigned char lif_f32(float I, float& v, float& r) {
  bool active = I > 0.0f;
  bool refrac = r > 0.0f;
  float vi = __fadd_rn(__fmul_rn(v, 0.95f), I);
  bool fired = active && !refrac && (vi >= 1.0f);
  float vn = !active ? v : ((refrac || fired) ? 0.0f : vi);
  float rn = !active ? r : (refrac ? (r - 1.0f) : (fired ? 2.0f : r));
  v = vn; r = rn;
  return fired ? (unsigned char)1 : (unsigned char)0;
}

// ---------------- hidden layer: fused encode + compaction + sparse sum, 2 rows/block
// Two batch rows per block: two INDEPENDENT accumulator chains interleaved per
// thread (2x memory-level parallelism). Within each row the rounded adds remain
// ascending-k within each KC panel, panels combined by one rounded add each —
// bit-identical to the gated-scan original. Inter-row interleave touches no
// within-row FP order.
__global__ __launch_bounds__(256) void hidden_k(
    const float* __restrict__ noise_t, const float* __restrict__ x,
    const float* __restrict__ rin_in, float* __restrict__ rin_out,
    unsigned char* __restrict__ in_spk,
    const float* __restrict__ W1T,
    float* __restrict__ v_h, float* __restrict__ r_h,
    unsigned char* __restrict__ hid_spk) {
  int tid = threadIdx.x;
  int h = blockIdx.x * 256 + tid;
  int b0 = blockIdx.y * 2, b1 = b0 + 1;
  __shared__ unsigned short s_idx0[IN], s_idx1[IN];
  __shared__ int s_off0[4], s_off1[4];
  __shared__ int wsum[4];

  // ---- fused encode: each thread owns k in [tid*4, tid*4+4) of both rows ----
  size_t e0 = (size_t)b0 * IN + (size_t)tid * 4;
  size_t e1 = (size_t)b1 * IN + (size_t)tid * 4;
  float4 xv0 = *reinterpret_cast<const float4*>(x + e0);
  float4 nv0 = *reinterpret_cast<const float4*>(noise_t + e0);
  float4 rv0 = *reinterpret_cast<const float4*>(rin_in + e0);
  float4 xv1 = *reinterpret_cast<const float4*>(x + e1);
  float4 nv1 = *reinterpret_cast<const float4*>(noise_t + e1);
  float4 rv1 = *reinterpret_cast<const float4*>(rin_in + e1);
  float px0[4] = {xv0.x, xv0.y, xv0.z, xv0.w}, pn0[4] = {nv0.x, nv0.y, nv0.z, nv0.w};
  float pr0[4] = {rv0.x, rv0.y, rv0.z, rv0.w};
  float px1[4] = {xv1.x, xv1.y, xv1.z, xv1.w}, pn1[4] = {nv1.x, nv1.y, nv1.z, nv1.w};
  float pr1[4] = {rv1.x, rv1.y, rv1.z, rv1.w};
  int f0[4], f1[4]; float rn0[4], rn1[4];
  #pragma unroll
  for (int j = 0; j < 4; j++) {
    float p = __fmul_rn(px0[j], 100.0f);
    p = fminf(fmaxf(p, 0.0f), 100.0f);
    p = __fmul_rn(p, 0.001f);
    bool s = pn0[j] < p;
    bool refrac = pr0[j] > 0.0f;
    bool fired = s && !refrac;           // input-layer v == 0 always (proven)
    rn0[j] = !s ? pr0[j] : (refrac ? (pr0[j] - 1.0f) : 2.0f);
    f0[j] = fired ? 1 : 0;
    p = __fmul_rn(px1[j], 100.0f);
    p = fminf(fmaxf(p, 0.0f), 100.0f);
    p = __fmul_rn(p, 0.001f);
    s = pn1[j] < p;
    refrac = pr1[j] > 0.0f;
    fired = s && !refrac;
    rn1[j] = !s ? pr1[j] : (refrac ? (pr1[j] - 1.0f) : 2.0f);
    f1[j] = fired ? 1 : 0;
  }
  if (blockIdx.x == 0) {                 // single owner commits state for both rows
    *reinterpret_cast<float4*>(rin_out + e0) = make_float4(rn0[0], rn0[1], rn0[2], rn0[3]);
    *reinterpret_cast<float4*>(rin_out + e1) = make_float4(rn1[0], rn1[1], rn1[2], rn1[3]);
    uchar4 sp0, sp1;
    sp0.x = (unsigned char)f0[0]; sp0.y = (unsigned char)f0[1];
    sp0.z = (unsigned char)f0[2]; sp0.w = (unsigned char)f0[3];
    sp1.x = (unsigned char)f1[0]; sp1.y = (unsigned char)f1[1];
    sp1.z = (unsigned char)f1[2]; sp1.w = (unsigned char)f1[3];
    *reinterpret_cast<uchar4*>(in_spk + e0) = sp0;
    *reinterpret_cast<uchar4*>(in_spk + e1) = sp1;
  }
  int cnt0 = f0[0] + f0[1] + f0[2] + f0[3];
  int cnt1 = f1[0] + f1[1] + f1[2] + f1[3];
  int pc = cnt0 | (cnt1 << 16);          // packed; counts <= 1024, no overflow

  // ---- block exclusive scan (packed both rows) ----
  int lane = tid & 63, wv = tid >> 6;
  int inc = pc;
  #pragma unroll
  for (int d = 1; d < 64; d <<= 1) {
    int nn = __shfl_up(inc, d, 64);
    if (lane >= d) inc += nn;
  }
  if (lane == 63) wsum[wv] = inc;
  __syncthreads();
  int wbase = 0;
  #pragma unroll
  for (int w = 0; w < 4; w++) if (w < wv) wbase += wsum[w];
  int epk = wbase + inc - pc;
  int excl0 = epk & 0xffff, excl1 = epk >> 16;

  int o0 = excl0, o1 = excl1, kb = tid * 4;
  #pragma unroll
  for (int j = 0; j < 4; j++) {
    if (f0[j]) s_idx0[o0++] = (unsigned short)(kb + j);
    if (f1[j]) s_idx1[o1++] = (unsigned short)(kb + j);
  }
  if (tid == 0)   { s_off0[0] = 0;      s_off1[0] = 0; }
  if (tid == 96)  { s_off0[1] = excl0;  s_off1[1] = excl1; }  // panel k=384
  if (tid == 192) { s_off0[2] = excl0;  s_off1[2] = excl1; }  // panel k=768
  if (tid == 255) { s_off0[3] = excl0 + cnt0; s_off1[3] = excl1 + cnt1; }
  __syncthreads();

  float tot0 = 0.0f, tot1 = 0.0f;
  const float* Wc = W1T + h;
  #pragma unroll
  for (int p = 0; p < 3; p++) {
    int ka = s_off0[p], kea = s_off0[p + 1];
    int kc2 = s_off1[p], keb = s_off1[p + 1];
    float pa = 0.0f, pb = 0.0f;
    while (ka + 4 <= kea && kc2 + 4 <= keb) {   // interleave 2 independent chains
      int a0 = s_idx0[ka], a1 = s_idx0[ka + 1], a2 = s_idx0[ka + 2], a3 = s_idx0[ka + 3];
      int c0 = s_idx1[kc2], c1 = s_idx1[kc2 + 1], c2 = s_idx1[kc2 + 2], c3 = s_idx1[kc2 + 3];
      float wa0 = Wc[(size_t)a0 * HID], wa1 = Wc[(size_t)a1 * HID];
      float wa2 = Wc[(size_t)a2 * HID], wa3 = Wc[(size_t)a3 * HID];
      float wb0 = Wc[(size_t)c0 * HID], wb1 = Wc[(size_t)c1 * HID];
      float wb2 = Wc[(size_t)c2 * HID], wb3 = Wc[(size_t)c3 * HID];
      pa = __fadd_rn(pa, wa0); pa = __fadd_rn(pa, wa1);
      pa = __fadd_rn(pa, wa2); pa = __fadd_rn(pa, wa3);
      pb = __fadd_rn(pb, wb0); pb = __fadd_rn(pb, wb1);
      pb = __fadd_rn(pb, wb2); pb = __fadd_rn(pb, wb3);
      ka += 4; kc2 += 4;
    }
    for (; ka + 4 <= kea; ka += 4) {
      int a0 = s_idx0[ka], a1 = s_idx0[ka + 1], a2 = s_idx0[ka + 2], a3 = s_idx0[ka + 3];
      float wa0 = Wc[(size_t)a0 * HID], wa1 = Wc[(size_t)a1 * HID];
      float wa2 = Wc[(size_t)a2 * HID], wa3 = Wc[(size_t)a3 * HID];
      pa = __fadd_rn(pa, wa0); pa = __fadd_rn(pa, wa1);
      pa = __fadd_rn(pa, wa2); pa = __fadd_rn(pa, wa3);
    }
    for (; kc2 + 4 <= keb; kc2 += 4) {
      int c0 = s_idx1[kc2], c1 = s_idx1[kc2 + 1], c2 = s_idx1[kc2 + 2], c3 = s_idx1[kc2 + 3];
      float wb0 = Wc[(size_t)c0 * HID], wb1 = Wc[(size_t)c1 * HID];
      float wb2 = Wc[(size_t)c2 * HID], wb3 = Wc[(size_t)c3 * HID];
      pb = __fadd_rn(pb, wb0); pb = __fadd_rn(pb, wb1);
      pb = __fadd_rn(pb, wb2); pb = __fadd_rn(pb, wb3);
    }
    for (; ka < kea; ka++) pa = __fadd_rn(pa, Wc[(size_t)s_idx0[ka] * HID]);
    for (; kc2 < keb; kc2++) pb = __fadd_rn(pb, Wc[(size_t)s_idx1[kc2] * HID]);
    tot0 = __fadd_rn(tot0, pa);          // first panel: rn(0+P0)=P0 exact
    tot1 = __fadd_rn(tot1, pb);
  }
  size_t i0 = (size_t)b0 * HID + h;
  size_t i1 = (size_t)b1 * HID + h;
  float v = v_h[i0], r = r_h[i0];
  hid_spk[i0] = lif_f32(tot0, v, r);
  v_h[i0] = v; r_h[i0] = r;
  v = v_h[i1]; r = r_h[i1];
  hid_spk[i1] = lif_f32(tot1, v, r);
  v_h[i1] = v; r_h[i1] = r;
}

// ---------------- output layer: compaction + sparse sum + LIF, 2 rows/block ------
__global__ __launch_bounds__(256) void out_k(const unsigned char* __restrict__ hid_spk,
                                             const float* __restrict__ W2T,
                                             float* __restrict__ v_o,
                                             float* __restrict__ r_o,
                                             float* __restrict__ out_acc) {
  int tid = threadIdx.x;
  int o = blockIdx.x * 256 + tid;
  int b0 = blockIdx.y * 2, b1 = b0 + 1;
  __shared__ unsigned short s_idx0[HID], s_idx1[HID];   // 16 KB
  __shared__ int s_off0[12], s_off1[12];  // 11 panels (4096 = 10*384 + 256) + total
  __shared__ int wsum[4];

  // each thread owns k in [tid*16, tid*16+16) of both rows
  uint4 u0 = *reinterpret_cast<const uint4*>(hid_spk + (size_t)b0 * HID + tid * 16);
  uint4 u1 = *reinterpret_cast<const uint4*>(hid_spk + (size_t)b1 * HID + tid * 16);
  unsigned w0[4] = {u0.x, u0.y, u0.z, u0.w};
  unsigned w1[4] = {u1.x, u1.y, u1.z, u1.w};
  int cnt0 = 0, cnt1 = 0;
  #pragma unroll
  for (int j = 0; j < 16; j++) {
    cnt0 += (w0[j >> 2] >> ((j & 3) * 8)) & 0xff;
    cnt1 += (w1[j >> 2] >> ((j & 3) * 8)) & 0xff;
  }
  int pc = cnt0 | (cnt1 << 16);          // counts <= 4096, packed scan safe

  int lane = tid & 63, wv = tid >> 6;
  int inc = pc;
  #pragma unroll
  for (int d = 1; d < 64; d <<= 1) {
    int nn = __shfl_up(inc, d, 64);
    if (lane >= d) inc += nn;
  }
  if (lane == 63) wsum[wv] = inc;
  __syncthreads();
  int wbase = 0;
  #pragma unroll
  for (int w = 0; w < 4; w++) if (w < wv) wbase += wsum[w];
  int epk = wbase + inc - pc;
  int excl0 = epk & 0xffff, excl1 = epk >> 16;

  int o0 = excl0, o1 = excl1, kb = tid * 16;
  #pragma unroll
  for (int j = 0; j < 16; j++) {
    if ((w0[j >> 2] >> ((j & 3) * 8)) & 0xff) s_idx0[o0++] = (unsigned short)(kb + j);
    if ((w1[j >> 2] >> ((j & 3) * 8)) & 0xff) s_idx1[o1++] = (unsigned short)(kb + j);
  }
  // panel p starts at k = 384*p -> thread 24*p (384/16 == 24, exact)
  if ((tid % 24) == 0 && tid <= 240) { s_off0[tid / 24] = excl0; s_off1[tid / 24] = excl1; }
  if (tid == 255) { s_off0[11] = excl0 + cnt0; s_off1[11] = excl1 + cnt1; }
  __syncthreads();

  float tot0 = 0.0f, tot1 = 0.0f;
  const float* Wc = W2T + o;
  #pragma unroll
  for (int p = 0; p < 11; p++) {
    int ka = s_off0[p], kea = s_off0[p + 1];
    int kc2 = s_off1[p], keb = s_off1[p + 1];
    float pa = 0.0f, pb = 0.0f;
    while (ka + 4 <= kea && kc2 + 4 <= keb) {   // interleave 2 independent chains
      int a0 = s_idx0[ka], a1 = s_idx0[ka + 1], a2 = s_idx0[ka + 2], a3 = s_idx0[ka + 3];
      int c0 = s_idx1[kc2], c1 = s_idx1[kc2 + 1], c2 = s_idx1[kc2 + 2], c3 = s_idx1[kc2 + 3];
      float wa0 = Wc[(size_t)a0 * OUTN], wa1 = Wc[(size_t)a1 * OUTN];
      float wa2 = Wc[(size_t)a2 * OUTN], wa3 = Wc[(size_t)a3 * OUTN];
      float wb0 = Wc[(size_t)c0 * OUTN], wb1 = Wc[(size_t)c1 * OUTN];
      float wb2 = Wc[(size_t)c2 * OUTN], wb3 = Wc[(size_t)c3 * OUTN];
      pa = __fadd_rn(pa, wa0); pa = __fadd_rn(pa, wa1);
      pa = __fadd_rn(pa, wa2); pa = __fadd_rn(pa, wa3);
      pb = __fadd_rn(pb, wb0); pb = __fadd_rn(pb, wb1);
      pb = __fadd_rn(pb, wb2); pb = __fadd_rn(pb, wb3);
      ka += 4; kc2 += 4;
    }
    for (; ka + 4 <= kea; ka += 4) {
      int a0 = s_idx0[ka], a1 = s_idx0[ka + 1], a2 = s_idx0[ka + 2], a3 = s_idx0[ka + 3];
      float wa0 = Wc[(size_t)a0 * OUTN], wa1 = Wc[(size_t)a1 * OUTN];
      float wa2 = Wc[(size_t)a2 * OUTN], wa3 = Wc[(size_t)a3 * OUTN];
      pa = __fadd_rn(pa, wa0); pa = __fadd_rn(pa, wa1);
      pa = __fadd_rn(pa, wa2); pa = __fadd_rn(pa, wa3);
    }
    for (; kc2 + 4 <= keb; kc2 += 4) {
      int c0 = s_idx1[kc2], c1 = s_idx1[kc2 + 1], c2 = s_idx1[kc2 + 2], c3 = s_idx1[kc2 + 3];
      float wb0 = Wc[(size_t)c0 * OUTN], wb1 = Wc[(size_t)c1 * OUTN];
      float wb2 = Wc[(size_t)c2 * OUTN], wb3 = Wc[(size_t)c3 * OUTN];
      pb = __fadd_rn(pb, wb0); pb = __fadd_rn(pb, wb1);
      pb = __fadd_rn(pb, wb2); pb = __fadd_rn(pb, wb3);
    }
    for (; ka < kea; ka++) pa = __fadd_rn(pa, Wc[(size_t)s_idx0[ka] * OUTN]);
    for (; kc2 < keb; kc2++) pb = __fadd_rn(pb, Wc[(size_t)s_idx1[kc2] * OUTN]);
    tot0 = __fadd_rn(tot0, pa);
    tot1 = __fadd_rn(tot1, pb);
  }
  size_t i0 = (size_t)b0 * OUTN + o;
  size_t i1 = (size_t)b1 * OUTN + o;
  float v = v_o[i0], r = r_o[i0];
  unsigned char fired = lif_f32(tot0, v, r);
  v_o[i0] = v; r_o[i0] = r;
  if (fired) out_acc[i0] = __fadd_rn(out_acc[i0], 1.0f);  // exact int count
  v = v_o[i1]; r = r_o[i1];
  fired = lif_f32(tot1, v, r);
  v_o[i1] = v; r_o[i1] = r;
  if (fired) out_acc[i1] = __fadd_rn(out_acc[i1], 1.0f);
}

// ---------------- STDP stats, two-phase (t % 10 == 0) ----------------
// Phase 1: packed byte-lane partial sums over 16-row chunks. Spike bytes are 0/1,
// per-byte totals <= 128 so packed u32 atomicAdd never carries across byte lanes
// -> exact integer column counts.
#define NWSTAT ((IN + HID) / 4)   // 1280 u32 words
__global__ __launch_bounds__(256) void stats1_k(
    const unsigned char* __restrict__ in_spk, const unsigned char* __restrict__ hid_spk,
    unsigned* __restrict__ pcnt) {
  int w = blockIdx.x * 256 + threadIdx.x;   // word index in [0, NWSTAT)
  int r0 = blockIdx.y * 16;                 // 8 chunks x 16 rows
  unsigned s = 0;
  if (w < IN / 4) {
    const unsigned* p = (const unsigned*)in_spk;
    #pragma unroll
    for (int b = 0; b < 16; b++) s += p[(size_t)(r0 + b) * (IN / 4) + w];
  } else {
    const unsigned* p = (const unsigned*)hid_spk;
    int w2 = w - IN / 4;
    #pragma unroll
    for (int b = 0; b < 16; b++) s += p[(size_t)(r0 + b) * (HID / 4) + w2];
  }
  atomicAdd(pcnt + w, s);
}

// Phase 2: exact counts -> pm, trace updates, flags (identical FP ops as before).
__global__ __launch_bounds__(256) void stats2_k(
    const unsigned* __restrict__ pcnt,
    float* __restrict__ pre_m, float* __restrict__ post_m,
    float* __restrict__ tp, float* __restrict__ tn, int* __restrict__ flags) {
  int c = blockIdx.x * 256 + threadIdx.x;   // column in [0, IN+HID)
  int cnt = (int)((pcnt[c >> 2] >> ((c & 3) * 8)) & 0xff);
  if (c < IN) {
    float pm = __fdiv_rn((float)cnt, 128.0f);       // exact (pow2)
    pre_m[c] = pm;
    tp[c] = __fadd_rn(__fmul_rn(0.9f, tp[c]), pm);  // tp_n committed (stdp step)
    if (cnt > 0) atomicOr(flags + 0, 1);
  } else {
    int h = c - IN;
    float pm = __fdiv_rn((float)cnt, 128.0f);
    post_m[h] = pm;
    tn[h] = __fadd_rn(__fmul_rn(0.9f, tn[h]), pm);
    if (cnt > 0) atomicOr(flags + 1, 1);
  }
}

__global__ __launch_bounds__(256) void apply_k(
    float* __restrict__ W1T,
    const float* __restrict__ tp, const float* __restrict__ tn,
    const float* __restrict__ pre_m, const float* __restrict__ post_m,
    const int* __restrict__ flags) {
  if (!(flags[0] && flags[1])) return;   // 'both' gate
  size_t idx = (size_t)blockIdx.x * 256 + threadIdx.x;  // i*HID + h layout
  int i = (int)(idx >> 12);
  int h = (int)(idx & 4095);
  float a  = __fmul_rn(tp[i], post_m[h]);     // tp already == tp_n
  float b2 = __fmul_rn(pre_m[i], tn[h]);      // tn already == tn_n
  float d  = __fmul_rn(0.001f, __fsub_rn(a, b2));
  float w  = __fadd_rn(W1T[idx], d);
  w = fminf(fmaxf(w, -1.0f), 1.0f);           // jnp.clip: max then min
  W1T[idx] = w;
}

__global__ __launch_bounds__(256) void scale_k(const float* __restrict__ acc,
                                               float* __restrict__ out) {
  int j = blockIdx.x * 256 + threadIdx.x;
  out[j] = __fdiv_rn(acc[j], 100.0f);
}

// ---------------- host launcher ----------------
extern "C" void kernel_launch(void* const* d_in, const int* in_sizes, int n_in,
                              void* d_out, int out_size, void* d_ws, size_t ws_size,
                              hipStream_t stream) {
  (void)in_sizes; (void)n_in; (void)out_size; (void)ws_size;
  const float* x     = (const float*)d_in[0];
  const float* W1    = (const float*)d_in[1];
  const float* W2    = (const float*)d_in[2];
  const float* noise = (const float*)d_in[3];

  char* ws = (char*)d_ws;
  size_t off = 0;
  auto alloc = [&](size_t bytes) -> char* {
    char* p = ws + off;
    off += (bytes + 255) & ~(size_t)255;
    return p;
  };
  float* W1T   = (float*)alloc((size_t)IN * HID * 4);     // 16 MB working copy (i-major)
  float* W2T   = (float*)alloc((size_t)HID * OUTN * 4);   // 16 MB (h-major)
  float* v_h   = (float*)alloc((size_t)BB * HID * 4);
  float* r_h   = (float*)alloc((size_t)BB * HID * 4);
  float* v_o   = (float*)alloc((size_t)BB * OUTN * 4);
  float* r_o   = (float*)alloc((size_t)BB * OUTN * 4);
  float* rinA  = (float*)alloc((size_t)BB * IN * 4);      // ping-pong refractory state
  float* rinB  = (float*)alloc((size_t)BB * IN * 4);
  float* acc   = (float*)alloc((size_t)BB * OUTN * 4);
  float* tp    = (float*)alloc((size_t)IN * 4);
  float* tn    = (float*)alloc((size_t)HID * 4);
  float* pre_m = (float*)alloc((size_t)IN * 4);
  float* post_m= (float*)alloc((size_t)HID * 4);
  unsigned char* in_spk  = (unsigned char*)alloc((size_t)BB * IN);
  unsigned char* hid_spk = (unsigned char*)alloc((size_t)BB * HID);
  unsigned* pcnt = (unsigned*)alloc((size_t)10 * NWSTAT * 4);  // per-STDP-step slots
  int* flags   = (int*)alloc(2 * 10 * sizeof(int));            // per-STDP-step slots

  // zero all state (ws is poisoned before every call)
  hipMemsetAsync(v_h, 0, (size_t)BB * HID * 4, stream);
  hipMemsetAsync(r_h, 0, (size_t)BB * HID * 4, stream);
  hipMemsetAsync(v_o, 0, (size_t)BB * OUTN * 4, stream);
  hipMemsetAsync(r_o, 0, (size_t)BB * OUTN * 4, stream);
  hipMemsetAsync(rinA, 0, (size_t)BB * IN * 4, stream);
  hipMemsetAsync(acc, 0, (size_t)BB * OUTN * 4, stream);
  hipMemsetAsync(tp,  0, (size_t)IN * 4, stream);
  hipMemsetAsync(tn,  0, (size_t)HID * 4, stream);
  hipMemsetAsync(pcnt, 0, (size_t)10 * NWSTAT * 4, stream);
  hipMemsetAsync(flags, 0, 2 * 10 * sizeof(int), stream);

  // W1 (HID x IN) -> W1T (IN x HID); W2 (OUTN x HID) -> W2T (HID x OUTN). Tiled.
  ttrans_k<<<dim3(IN / 32, HID / 32), 256, 0, stream>>>(W1, W1T, HID, IN);
  ttrans_k<<<dim3(HID / 32, OUTN / 32), 256, 0, stream>>>(W2, W2T, OUTN, HID);

  float* rin_in = rinA;
  float* rin_out = rinB;
  for (int t = 0; t < TSTEPS; t++) {
    const float* nz = noise + (size_t)t * BB * IN;
    hidden_k<<<dim3(HID / 256, BB / 2), 256, 0, stream>>>(nz, x, rin_in, rin_out, in_spk,
                                                          W1T, v_h, r_h, hid_spk);
    out_k<<<dim3(OUTN / 256, BB / 2), 256, 0, stream>>>(hid_spk, W2T, v_o, r_o, acc);
    if (t % 10 == 0) {
      unsigned* pc = pcnt + (size_t)NWSTAT * (t / 10);
      int* fl = flags + 2 * (t / 10);
      stats1_k<<<dim3(NWSTAT / 256, 8), 256, 0, stream>>>(in_spk, hid_spk, pc);
      stats2_k<<<(IN + HID) / 256, 256, 0, stream>>>(pc, pre_m, post_m, tp, tn, fl);
      apply_k<<<(IN * HID) / 256, 256, 0, stream>>>(W1T, tp, tn, pre_m, post_m, fl);
    }
    float* tmpp = rin_in; rin_in = rin_out; rin_out = tmpp;
  }
  scale_k<<<(BB * OUTN) / 256, 256, 0, stream>>>(acc, (float*)d_out);
}

// Round 5
// 3056.629 us; speedup vs baseline: 1.5683x; 1.5683x over previous
//
#include <hip/hip_runtime.h>
#include <cstdint>
#include <cstddef>

#define BB   128
#define IN   1024
#define HID  4096
#define OUTN 1024
#define TSTEPS 100
#define KC   384   // OpenBLAS SGEMM_DEFAULT_Q — panel structure must be preserved exactly

// ---------------- tiled transpose: dst[c*R + r] = src[r*C + c] ----------------
__global__ __launch_bounds__(256) void ttrans_k(const float* __restrict__ src,
                                                float* __restrict__ dst,
                                                int R, int C) {
  __shared__ float tile[32][33];
  int tx = threadIdx.x & 31;
  int ty = threadIdx.x >> 5;            // 0..7
  int c0 = blockIdx.x * 32, r0 = blockIdx.y * 32;
  #pragma unroll
  for (int j = 0; j < 32; j += 8)
    tile[ty + j][tx] = src[(size_t)(r0 + ty + j) * C + (c0 + tx)];
  __syncthreads();
  #pragma unroll
  for (int j = 0; j < 32; j += 8)
    dst[(size_t)(c0 + ty + j) * R + (r0 + tx)] = tile[tx][ty + j];
}

// f32 LIF exactly mirroring the reference op order (no FMA contraction).
__device__ __forceinline__ unsigned char lif_f32(float I, float& v, float& r) {
  bool active = I > 0.0f;
  bool refrac = r > 0.0f;
  float vi = __fadd_rn(__fmul_rn(v, 0.95f), I);
  bool fired = active && !refrac && (vi >= 1.0f);
  float vn = !active ? v : ((refrac || fired) ? 0.0f : vi);
  float rn = !active ? r : (refrac ? (r - 1.0f) : (fired ? 2.0f : r));
  v = vn; r = rn;
  return fired ? (unsigned char)1 : (unsigned char)0;
}

// ---------------- hidden layer: fused encode + compaction + sparse panel sum ------
// 1 batch row per block (measured faster than 2-row variant: full grid occupancy
// beats dual-chain MLP). Encode recomputed redundantly by all 16 blocks of a row;
// block.x==0 commits rin state (ping-pong) and in_spk for stats.
// Bit-exactness: within each KC panel the gated ascending-k adds are identical to
// iterating only the spiking k in ascending order (skipped adds were no-ops).
// Panels combined via one rounded add each. The 4-wide unroll only batches the
// loads; the adds remain in ascending-k order.
__global__ __launch_bounds__(256) void hidden_k(
    const float* __restrict__ noise_t, const float* __restrict__ x,
    const float* __restrict__ rin_in, float* __restrict__ rin_out,
    unsigned char* __restrict__ in_spk,
    const float* __restrict__ W1T,
    float* __restrict__ v_h, float* __restrict__ r_h,
    unsigned char* __restrict__ hid_spk) {
  int tid = threadIdx.x;
  int h = blockIdx.x * 256 + tid;
  int b = blockIdx.y;
  __shared__ unsigned short s_idx[IN];   // compacted ascending spike indices
  __shared__ int s_off[4];               // panel start offsets: 0, <384, <768, total
  __shared__ int wsum[4];

  // ---- fused encode: each thread owns k in [tid*4, tid*4+4) ----
  size_t ebase = (size_t)b * IN + (size_t)tid * 4;
  const float4 xv = *reinterpret_cast<const float4*>(x + ebase);
  const float4 nv = *reinterpret_cast<const float4*>(noise_t + ebase);
  const float4 rv = *reinterpret_cast<const float4*>(rin_in + ebase);
  float px[4] = {xv.x, xv.y, xv.z, xv.w};
  float pn[4] = {nv.x, nv.y, nv.z, nv.w};
  float pr[4] = {rv.x, rv.y, rv.z, rv.w};
  int f[4]; float rn[4];
  #pragma unroll
  for (int j = 0; j < 4; j++) {
    float p = __fmul_rn(px[j], 100.0f);
    p = fminf(fmaxf(p, 0.0f), 100.0f);
    p = __fmul_rn(p, 0.001f);
    bool s = pn[j] < p;                  // Bernoulli encode (strict <)
    bool refrac = pr[j] > 0.0f;
    bool fired = s && !refrac;           // input-layer v == 0 always (proven)
    rn[j] = !s ? pr[j] : (refrac ? (pr[j] - 1.0f) : 2.0f);
    f[j] = fired ? 1 : 0;
  }
  if (blockIdx.x == 0) {                 // single owner commits state
    *reinterpret_cast<float4*>(rin_out + ebase) = make_float4(rn[0], rn[1], rn[2], rn[3]);
    uchar4 sp; sp.x = (unsigned char)f[0]; sp.y = (unsigned char)f[1];
    sp.z = (unsigned char)f[2]; sp.w = (unsigned char)f[3];
    *reinterpret_cast<uchar4*>(in_spk + ebase) = sp;
  }
  int cnt = f[0] + f[1] + f[2] + f[3];

  // ---- block exclusive scan: wave-inclusive shfl scan + cross-wave combine ----
  int lane = tid & 63, wv = tid >> 6;
  int inc = cnt;
  #pragma unroll
  for (int d = 1; d < 64; d <<= 1) {
    int nn = __shfl_up(inc, d, 64);
    if (lane >= d) inc += nn;
  }
  if (lane == 63) wsum[wv] = inc;
  __syncthreads();
  int wbase = 0;
  #pragma unroll
  for (int w = 0; w < 4; w++) if (w < wv) wbase += wsum[w];
  int excl = wbase + inc - cnt;

  int o = excl, kb = tid * 4;
  if (f[0]) s_idx[o++] = (unsigned short)(kb);
  if (f[1]) s_idx[o++] = (unsigned short)(kb + 1);
  if (f[2]) s_idx[o++] = (unsigned short)(kb + 2);
  if (f[3]) s_idx[o++] = (unsigned short)(kb + 3);
  if (tid == 0)   s_off[0] = 0;          // panel k=0    starts at thread 0
  if (tid == 96)  s_off[1] = excl;       // panel k=384  starts at thread 96
  if (tid == 192) s_off[2] = excl;       // panel k=768  starts at thread 192
  if (tid == 255) s_off[3] = excl + cnt; // total spike count
  __syncthreads();

  float total = 0.0f;
  const float* Wc = W1T + h;
  #pragma unroll
  for (int p = 0; p < 3; p++) {
    int ks = s_off[p], ke = s_off[p + 1];
    float part = 0.0f;
    int k = ks;
    for (; k + 4 <= ke; k += 4) {        // batch 4 independent loads, ordered adds
      int k0 = s_idx[k], k1 = s_idx[k + 1], k2 = s_idx[k + 2], k3 = s_idx[k + 3];
      float w0 = Wc[(size_t)k0 * HID];
      float w1 = Wc[(size_t)k1 * HID];
      float w2 = Wc[(size_t)k2 * HID];
      float w3 = Wc[(size_t)k3 * HID];
      part = __fadd_rn(part, w0);
      part = __fadd_rn(part, w1);
      part = __fadd_rn(part, w2);
      part = __fadd_rn(part, w3);
    }
    for (; k < ke; k++) part = __fadd_rn(part, Wc[(size_t)s_idx[k] * HID]);
    total = __fadd_rn(total, part);      // first panel: rn(0+P0)=P0 exact
  }
  size_t idx = (size_t)b * HID + h;
  float v = v_h[idx], r = r_h[idx];
  hid_spk[idx] = lif_f32(total, v, r);
  v_h[idx] = v; r_h[idx] = r;
}

// ---------------- output layer: in-block compaction + sparse panel sum + LIF ------
__global__ __launch_bounds__(256) void out_k(const unsigned char* __restrict__ hid_spk,
                                             const float* __restrict__ W2T,
                                             float* __restrict__ v_o,
                                             float* __restrict__ r_o,
                                             float* __restrict__ out_acc) {
  int tid = threadIdx.x;
  int o = blockIdx.x * 256 + tid;
  int b = blockIdx.y;
  __shared__ unsigned short s_idx[HID];  // 8 KB
  __shared__ int s_off[12];              // 11 panels (4096 = 10*384 + 256) + total
  __shared__ int wsum[4];

  // each thread owns k in [tid*16, tid*16+16)
  uint4 u = *reinterpret_cast<const uint4*>(hid_spk + (size_t)b * HID + tid * 16);
  unsigned ww[4] = {u.x, u.y, u.z, u.w};
  int cnt = 0;
  #pragma unroll
  for (int j = 0; j < 16; j++) cnt += (ww[j >> 2] >> ((j & 3) * 8)) & 0xff;

  int lane = tid & 63, wv = tid >> 6;
  int inc = cnt;
  #pragma unroll
  for (int d = 1; d < 64; d <<= 1) {
    int nn = __shfl_up(inc, d, 64);
    if (lane >= d) inc += nn;
  }
  if (lane == 63) wsum[wv] = inc;
  __syncthreads();
  int wbase = 0;
  #pragma unroll
  for (int w = 0; w < 4; w++) if (w < wv) wbase += wsum[w];
  int excl = wbase + inc - cnt;

  int oo = excl, kb = tid * 16;
  #pragma unroll
  for (int j = 0; j < 16; j++) {
    if ((ww[j >> 2] >> ((j & 3) * 8)) & 0xff) s_idx[oo++] = (unsigned short)(kb + j);
  }
  // panel p starts at k = 384*p -> thread 24*p (384/16 == 24, exact)
  if ((tid % 24) == 0 && tid <= 240) s_off[tid / 24] = excl;
  if (tid == 255) s_off[11] = excl + cnt;
  __syncthreads();

  float total = 0.0f;
  const float* Wc = W2T + o;
  #pragma unroll
  for (int p = 0; p < 11; p++) {
    int ks = s_off[p], ke = s_off[p + 1];
    float part = 0.0f;
    int k = ks;
    for (; k + 8 <= ke; k += 8) {        // batch 8 independent loads, ordered adds
      int k0 = s_idx[k],     k1 = s_idx[k + 1], k2 = s_idx[k + 2], k3 = s_idx[k + 3];
      int k4 = s_idx[k + 4], k5 = s_idx[k + 5], k6 = s_idx[k + 6], k7 = s_idx[k + 7];
      float w0 = Wc[(size_t)k0 * OUTN];
      float w1 = Wc[(size_t)k1 * OUTN];
      float w2 = Wc[(size_t)k2 * OUTN];
      float w3 = Wc[(size_t)k3 * OUTN];
      float w4 = Wc[(size_t)k4 * OUTN];
      float w5 = Wc[(size_t)k5 * OUTN];
      float w6 = Wc[(size_t)k6 * OUTN];
      float w7 = Wc[(size_t)k7 * OUTN];
      part = __fadd_rn(part, w0);
      part = __fadd_rn(part, w1);
      part = __fadd_rn(part, w2);
      part = __fadd_rn(part, w3);
      part = __fadd_rn(part, w4);
      part = __fadd_rn(part, w5);
      part = __fadd_rn(part, w6);
      part = __fadd_rn(part, w7);
    }
    if (k + 4 <= ke) {
      int k0 = s_idx[k], k1 = s_idx[k + 1], k2 = s_idx[k + 2], k3 = s_idx[k + 3];
      float w0 = Wc[(size_t)k0 * OUTN];
      float w1 = Wc[(size_t)k1 * OUTN];
      float w2 = Wc[(size_t)k2 * OUTN];
      float w3 = Wc[(size_t)k3 * OUTN];
      part = __fadd_rn(part, w0);
      part = __fadd_rn(part, w1);
      part = __fadd_rn(part, w2);
      part = __fadd_rn(part, w3);
      k += 4;
    }
    for (; k < ke; k++) part = __fadd_rn(part, Wc[(size_t)s_idx[k] * OUTN]);
    total = __fadd_rn(total, part);
  }
  size_t idx = (size_t)b * OUTN + o;
  float v = v_o[idx], r = r_o[idx];
  unsigned char fired = lif_f32(total, v, r);
  v_o[idx] = v; r_o[idx] = r;
  if (fired) out_acc[idx] = __fadd_rn(out_acc[idx], 1.0f);  // exact int count
}

// ---------------- STDP stats, two-phase (t % 10 == 0) ----------------
// Phase 1: packed byte-lane partial sums over 16-row chunks. Spike bytes are 0/1,
// per-byte totals <= 128 so packed u32 atomicAdd never carries across byte lanes
// -> exact integer column counts. atomicAdd targets are DISTINCT per thread (no
// same-address contention; 8 y-blocks per address).
#define NWSTAT ((IN + HID) / 4)   // 1280 u32 words
__global__ __launch_bounds__(256) void stats1_k(
    const unsigned char* __restrict__ in_spk, const unsigned char* __restrict__ hid_spk,
    unsigned* __restrict__ pcnt) {
  int w = blockIdx.x * 256 + threadIdx.x;   // word index in [0, NWSTAT)
  int r0 = blockIdx.y * 16;                 // 8 chunks x 16 rows
  unsigned s = 0;
  if (w < IN / 4) {
    const unsigned* p = (const unsigned*)in_spk;
    #pragma unroll
    for (int b = 0; b < 16; b++) s += p[(size_t)(r0 + b) * (IN / 4) + w];
  } else {
    const unsigned* p = (const unsigned*)hid_spk;
    int w2 = w - IN / 4;
    #pragma unroll
    for (int b = 0; b < 16; b++) s += p[(size_t)(r0 + b) * (HID / 4) + w2];
  }
  atomicAdd(pcnt + w, s);
}

// Phase 2: exact counts -> pm, trace updates, flags. The 'both' flags use a wave
// ballot + ONE atomic per wave: the previous per-thread atomicOr (5120 atomics to
// 2 addresses) serialized at ~25cy each = the measured 59us. Waves never straddle
// the IN boundary (IN = 4 blocks exactly).
__global__ __launch_bounds__(256) void stats2_k(
    const unsigned* __restrict__ pcnt,
    float* __restrict__ pre_m, float* __restrict__ post_m,
    float* __restrict__ tp, float* __restrict__ tn, int* __restrict__ flags) {
  int c = blockIdx.x * 256 + threadIdx.x;   // column in [0, IN+HID)
  int cnt = (int)((pcnt[c >> 2] >> ((c & 3) * 8)) & 0xff);
  int lane = threadIdx.x & 63;
  if (c < IN) {
    float pm = __fdiv_rn((float)cnt, 128.0f);       // exact (pow2)
    pre_m[c] = pm;
    tp[c] = __fadd_rn(__fmul_rn(0.9f, tp[c]), pm);  // tp_n committed (stdp step)
    unsigned long long any = __ballot(cnt > 0);
    if (any && lane == 0) atomicOr(flags + 0, 1);   // one atomic per wave
  } else {
    int h = c - IN;
    float pm = __fdiv_rn((float)cnt, 128.0f);
    post_m[h] = pm;
    tn[h] = __fadd_rn(__fmul_rn(0.9f, tn[h]), pm);
    unsigned long long any = __ballot(cnt > 0);
    if (any && lane == 0) atomicOr(flags + 1, 1);
  }
}

__global__ __launch_bounds__(256) void apply_k(
    float* __restrict__ W1T,
    const float* __restrict__ tp, const float* __restrict__ tn,
    const float* __restrict__ pre_m, const float* __restrict__ post_m,
    const int* __restrict__ flags) {
  if (!(flags[0] && flags[1])) return;   // 'both' gate
  size_t idx = (size_t)blockIdx.x * 256 + threadIdx.x;  // i*HID + h layout
  int i = (int)(idx >> 12);
  int h = (int)(idx & 4095);
  float a  = __fmul_rn(tp[i], post_m[h]);     // tp already == tp_n
  float b2 = __fmul_rn(pre_m[i], tn[h]);      // tn already == tn_n
  float d  = __fmul_rn(0.001f, __fsub_rn(a, b2));
  float w  = __fadd_rn(W1T[idx], d);
  w = fminf(fmaxf(w, -1.0f), 1.0f);           // jnp.clip: max then min
  W1T[idx] = w;
}

__global__ __launch_bounds__(256) void scale_k(const float* __restrict__ acc,
                                               float* __restrict__ out) {
  int j = blockIdx.x * 256 + threadIdx.x;
  out[j] = __fdiv_rn(acc[j], 100.0f);
}

// ---------------- host launcher ----------------
extern "C" void kernel_launch(void* const* d_in, const int* in_sizes, int n_in,
                              void* d_out, int out_size, void* d_ws, size_t ws_size,
                              hipStream_t stream) {
  (void)in_sizes; (void)n_in; (void)out_size; (void)ws_size;
  const float* x     = (const float*)d_in[0];
  const float* W1    = (const float*)d_in[1];
  const float* W2    = (const float*)d_in[2];
  const float* noise = (const float*)d_in[3];

  char* ws = (char*)d_ws;
  size_t off = 0;
  auto alloc = [&](size_t bytes) -> char* {
    char* p = ws + off;
    off += (bytes + 255) & ~(size_t)255;
    return p;
  };
  float* W1T   = (float*)alloc((size_t)IN * HID * 4);     // 16 MB working copy (i-major)
  float* W2T   = (float*)alloc((size_t)HID * OUTN * 4);   // 16 MB (h-major)
  float* v_h   = (float*)alloc((size_t)BB * HID * 4);
  float* r_h   = (float*)alloc((size_t)BB * HID * 4);
  float* v_o   = (float*)alloc((size_t)BB * OUTN * 4);
  float* r_o   = (float*)alloc((size_t)BB * OUTN * 4);
  float* rinA  = (float*)alloc((size_t)BB * IN * 4);      // ping-pong refractory state
  float* rinB  = (float*)alloc((size_t)BB * IN * 4);
  float* acc   = (float*)alloc((size_t)BB * OUTN * 4);
  float* tp    = (float*)alloc((size_t)IN * 4);
  float* tn    = (float*)alloc((size_t)HID * 4);
  float* pre_m = (float*)alloc((size_t)IN * 4);
  float* post_m= (float*)alloc((size_t)HID * 4);
  unsigned char* in_spk  = (unsigned char*)alloc((size_t)BB * IN);
  unsigned char* hid_spk = (unsigned char*)alloc((size_t)BB * HID);
  unsigned* pcnt = (unsigned*)alloc((size_t)10 * NWSTAT * 4);  // per-STDP-step slots
  int* flags   = (int*)alloc(2 * 10 * sizeof(int));            // per-STDP-step slots

  // zero all state (ws is poisoned before every call)
  hipMemsetAsync(v_h, 0, (size_t)BB * HID * 4, stream);
  hipMemsetAsync(r_h, 0, (size_t)BB * HID * 4, stream);
  hipMemsetAsync(v_o, 0, (size_t)BB * OUTN * 4, stream);
  hipMemsetAsync(r_o, 0, (size_t)BB * OUTN * 4, stream);
  hipMemsetAsync(rinA, 0, (size_t)BB * IN * 4, stream);
  hipMemsetAsync(acc, 0, (size_t)BB * OUTN * 4, stream);
  hipMemsetAsync(tp,  0, (size_t)IN * 4, stream);
  hipMemsetAsync(tn,  0, (size_t)HID * 4, stream);
  hipMemsetAsync(pcnt, 0, (size_t)10 * NWSTAT * 4, stream);
  hipMemsetAsync(flags, 0, 2 * 10 * sizeof(int), stream);

  // W1 (HID x IN) -> W1T (IN x HID); W2 (OUTN x HID) -> W2T (HID x OUTN). Tiled.
  ttrans_k<<<dim3(IN / 32, HID / 32), 256, 0, stream>>>(W1, W1T, HID, IN);
  ttrans_k<<<dim3(HID / 32, OUTN / 32), 256, 0, stream>>>(W2, W2T, OUTN, HID);

  float* rin_in = rinA;
  float* rin_out = rinB;
  for (int t = 0; t < TSTEPS; t++) {
    const float* nz = noise + (size_t)t * BB * IN;
    hidden_k<<<dim3(HID / 256, BB), 256, 0, stream>>>(nz, x, rin_in, rin_out, in_spk,
                                                      W1T, v_h, r_h, hid_spk);
    out_k<<<dim3(OUTN / 256, BB), 256, 0, stream>>>(hid_spk, W2T, v_o, r_o, acc);
    if (t % 10 == 0) {
      unsigned* pc = pcnt + (size_t)NWSTAT * (t / 10);
      int* fl = flags + 2 * (t / 10);
      stats1_k<<<dim3(NWSTAT / 256, 8), 256, 0, stream>>>(in_spk, hid_spk, pc);
      stats2_k<<<(IN + HID) / 256, 256, 0, stream>>>(pc, pre_m, post_m, tp, tn, fl);
      apply_k<<<(IN * HID) / 256, 256, 0, stream>>>(W1T, tp, tn, pre_m, post_m, fl);
    }
    float* tmpp = rin_in; rin_in = rin_out; rin_out = tmpp;
  }
  scale_k<<<(BB * OUTN) / 256, 256, 0, stream>>>(acc, (float*)d_out);
}

// Round 6
// 2242.586 us; speedup vs baseline: 2.1376x; 1.3630x over previous
//
#include <hip/hip_runtime.h>
#include <cstdint>
#include <cstddef>

#define BB   128
#define IN   1024
#define HID  4096
#define OUTN 1024
#define TSTEPS 100
#define KC   384   // OpenBLAS SGEMM_DEFAULT_Q — panel structure must be preserved exactly

// ---------------- tiled transpose: dst[c*R + r] = src[r*C + c] ----------------
__global__ __launch_bounds__(256) void ttrans_k(const float* __restrict__ src,
                                                float* __restrict__ dst,
                                                int R, int C) {
  __shared__ float tile[32][33];
  int tx = threadIdx.x & 31;
  int ty = threadIdx.x >> 5;            // 0..7
  int c0 = blockIdx.x * 32, r0 = blockIdx.y * 32;
  #pragma unroll
  for (int j = 0; j < 32; j += 8)
    tile[ty + j][tx] = src[(size_t)(r0 + ty + j) * C + (c0 + tx)];
  __syncthreads();
  #pragma unroll
  for (int j = 0; j < 32; j += 8)
    dst[(size_t)(c0 + ty + j) * R + (r0 + tx)] = tile[tx][ty + j];
}

// f32 LIF exactly mirroring the reference op order (no FMA contraction).
__device__ __forceinline__ unsigned char lif_f32(float I, float& v, float& r) {
  bool active = I > 0.0f;
  bool refrac = r > 0.0f;
  float vi = __fadd_rn(__fmul_rn(v, 0.95f), I);
  bool fired = active && !refrac && (vi >= 1.0f);
  float vn = !active ? v : ((refrac || fired) ? 0.0f : vi);
  float rn = !active ? r : (refrac ? (r - 1.0f) : (fired ? 2.0f : r));
  v = vn; r = rn;
  return fired ? (unsigned char)1 : (unsigned char)0;
}

// ---------------- hidden layer: fused encode + compaction + sparse panel sum ------
// 1 batch row per block. Encode recomputed redundantly by all 16 blocks of a row;
// block.x==0 commits rin state (ping-pong) and in_spk for stats.
// Bit-exactness: within each KC panel the gated ascending-k adds are identical to
// iterating only the spiking k in ascending order (skipped adds were no-ops).
// Panels combined via one rounded add each. The 8/4-wide unroll only batches the
// loads; the adds remain in ascending-k order.
__global__ __launch_bounds__(256) void hidden_k(
    const float* __restrict__ noise_t, const float* __restrict__ x,
    const float* __restrict__ rin_in, float* __restrict__ rin_out,
    unsigned char* __restrict__ in_spk,
    const float* __restrict__ W1T,
    float* __restrict__ v_h, float* __restrict__ r_h,
    unsigned char* __restrict__ hid_spk) {
  int tid = threadIdx.x;
  int h = blockIdx.x * 256 + tid;
  int b = blockIdx.y;
  __shared__ unsigned short s_idx[IN];   // compacted ascending spike indices
  __shared__ int s_off[4];               // panel start offsets: 0, <384, <768, total
  __shared__ int wsum[4];

  // ---- fused encode: each thread owns k in [tid*4, tid*4+4) ----
  size_t ebase = (size_t)b * IN + (size_t)tid * 4;
  const float4 xv = *reinterpret_cast<const float4*>(x + ebase);
  const float4 nv = *reinterpret_cast<const float4*>(noise_t + ebase);
  const float4 rv = *reinterpret_cast<const float4*>(rin_in + ebase);
  float px[4] = {xv.x, xv.y, xv.z, xv.w};
  float pn[4] = {nv.x, nv.y, nv.z, nv.w};
  float pr[4] = {rv.x, rv.y, rv.z, rv.w};
  int f[4]; float rn[4];
  #pragma unroll
  for (int j = 0; j < 4; j++) {
    float p = __fmul_rn(px[j], 100.0f);
    p = fminf(fmaxf(p, 0.0f), 100.0f);
    p = __fmul_rn(p, 0.001f);
    bool s = pn[j] < p;                  // Bernoulli encode (strict <)
    bool refrac = pr[j] > 0.0f;
    bool fired = s && !refrac;           // input-layer v == 0 always (proven)
    rn[j] = !s ? pr[j] : (refrac ? (pr[j] - 1.0f) : 2.0f);
    f[j] = fired ? 1 : 0;
  }
  if (blockIdx.x == 0) {                 // single owner commits state
    *reinterpret_cast<float4*>(rin_out + ebase) = make_float4(rn[0], rn[1], rn[2], rn[3]);
    uchar4 sp; sp.x = (unsigned char)f[0]; sp.y = (unsigned char)f[1];
    sp.z = (unsigned char)f[2]; sp.w = (unsigned char)f[3];
    *reinterpret_cast<uchar4*>(in_spk + ebase) = sp;
  }
  int cnt = f[0] + f[1] + f[2] + f[3];

  // ---- block exclusive scan: wave-inclusive shfl scan + cross-wave combine ----
  int lane = tid & 63, wv = tid >> 6;
  int inc = cnt;
  #pragma unroll
  for (int d = 1; d < 64; d <<= 1) {
    int nn = __shfl_up(inc, d, 64);
    if (lane >= d) inc += nn;
  }
  if (lane == 63) wsum[wv] = inc;
  __syncthreads();
  int wbase = 0;
  #pragma unroll
  for (int w = 0; w < 4; w++) if (w < wv) wbase += wsum[w];
  int excl = wbase + inc - cnt;

  int o = excl, kb = tid * 4;
  if (f[0]) s_idx[o++] = (unsigned short)(kb);
  if (f[1]) s_idx[o++] = (unsigned short)(kb + 1);
  if (f[2]) s_idx[o++] = (unsigned short)(kb + 2);
  if (f[3]) s_idx[o++] = (unsigned short)(kb + 3);
  if (tid == 0)   s_off[0] = 0;          // panel k=0    starts at thread 0
  if (tid == 96)  s_off[1] = excl;       // panel k=384  starts at thread 96
  if (tid == 192) s_off[2] = excl;       // panel k=768  starts at thread 192
  if (tid == 255) s_off[3] = excl + cnt; // total spike count
  __syncthreads();

  float total = 0.0f;
  const float* Wc = W1T + h;
  #pragma unroll
  for (int p = 0; p < 3; p++) {
    int ks = s_off[p], ke = s_off[p + 1];
    float part = 0.0f;
    int k = ks;
    for (; k + 8 <= ke; k += 8) {        // batch 8 independent loads, ordered adds
      int k0 = s_idx[k],     k1 = s_idx[k + 1], k2 = s_idx[k + 2], k3 = s_idx[k + 3];
      int k4 = s_idx[k + 4], k5 = s_idx[k + 5], k6 = s_idx[k + 6], k7 = s_idx[k + 7];
      float w0 = Wc[(size_t)k0 * HID];
      float w1 = Wc[(size_t)k1 * HID];
      float w2 = Wc[(size_t)k2 * HID];
      float w3 = Wc[(size_t)k3 * HID];
      float w4 = Wc[(size_t)k4 * HID];
      float w5 = Wc[(size_t)k5 * HID];
      float w6 = Wc[(size_t)k6 * HID];
      float w7 = Wc[(size_t)k7 * HID];
      part = __fadd_rn(part, w0);
      part = __fadd_rn(part, w1);
      part = __fadd_rn(part, w2);
      part = __fadd_rn(part, w3);
      part = __fadd_rn(part, w4);
      part = __fadd_rn(part, w5);
      part = __fadd_rn(part, w6);
      part = __fadd_rn(part, w7);
    }
    if (k + 4 <= ke) {
      int k0 = s_idx[k], k1 = s_idx[k + 1], k2 = s_idx[k + 2], k3 = s_idx[k + 3];
      float w0 = Wc[(size_t)k0 * HID];
      float w1 = Wc[(size_t)k1 * HID];
      float w2 = Wc[(size_t)k2 * HID];
      float w3 = Wc[(size_t)k3 * HID];
      part = __fadd_rn(part, w0);
      part = __fadd_rn(part, w1);
      part = __fadd_rn(part, w2);
      part = __fadd_rn(part, w3);
      k += 4;
    }
    for (; k < ke; k++) part = __fadd_rn(part, Wc[(size_t)s_idx[k] * HID]);
    total = __fadd_rn(total, part);      // first panel: rn(0+P0)=P0 exact
  }
  size_t idx = (size_t)b * HID + h;
  float v = v_h[idx], r = r_h[idx];
  hid_spk[idx] = lif_f32(total, v, r);
  v_h[idx] = v; r_h[idx] = r;
}

// ---------------- output layer: wave-split panels + compaction + LIF --------------
// Block covers 64 output columns; the 11 KC panels are split across the 4 waves
// (kg 0..3 -> panels {0-2},{3-5},{6-8},{9,10}). Each wave computes its panels'
// chains EXACTLY as the sequential version (independent ascending-k chains) into
// LDS parts[11][64]; wave 0 then does the same ordered left-fold + LIF. Grid
// (16,128) = 2048 blocks -> 4x the previous TLP; serial vmcnt waits per wave
// drop ~26 -> ~7.
__global__ __launch_bounds__(256) void out_k(const unsigned char* __restrict__ hid_spk,
                                             const float* __restrict__ W2T,
                                             float* __restrict__ v_o,
                                             float* __restrict__ r_o,
                                             float* __restrict__ out_acc) {
  int tid = threadIdx.x;
  int col = tid & 63;                    // output column within block
  int kg  = tid >> 6;                    // wave id = panel group
  int o = blockIdx.x * 64 + col;
  int b = blockIdx.y;
  __shared__ unsigned short s_idx[HID];  // 8 KB
  __shared__ int s_off[12];              // 11 panels (4096 = 10*384 + 256) + total
  __shared__ int wsum[4];
  __shared__ float parts[11][64];        // 2.75 KB; col-indexed -> conflict-free

  // each thread owns k in [tid*16, tid*16+16)
  uint4 u = *reinterpret_cast<const uint4*>(hid_spk + (size_t)b * HID + tid * 16);
  unsigned ww[4] = {u.x, u.y, u.z, u.w};
  int cnt = 0;
  #pragma unroll
  for (int j = 0; j < 16; j++) cnt += (ww[j >> 2] >> ((j & 3) * 8)) & 0xff;

  int lane = tid & 63, wv = tid >> 6;
  int inc = cnt;
  #pragma unroll
  for (int d = 1; d < 64; d <<= 1) {
    int nn = __shfl_up(inc, d, 64);
    if (lane >= d) inc += nn;
  }
  if (lane == 63) wsum[wv] = inc;
  __syncthreads();
  int wbase = 0;
  #pragma unroll
  for (int w = 0; w < 4; w++) if (w < wv) wbase += wsum[w];
  int excl = wbase + inc - cnt;

  int oo = excl, kb = tid * 16;
  #pragma unroll
  for (int j = 0; j < 16; j++) {
    if ((ww[j >> 2] >> ((j & 3) * 8)) & 0xff) s_idx[oo++] = (unsigned short)(kb + j);
  }
  // panel p starts at k = 384*p -> thread 24*p (384/16 == 24, exact)
  if ((tid % 24) == 0 && tid <= 240) s_off[tid / 24] = excl;
  if (tid == 255) s_off[11] = excl + cnt;
  __syncthreads();

  const int pstart = (kg == 0) ? 0 : (kg == 1) ? 3 : (kg == 2) ? 6 : 9;
  const int pend   = (kg == 0) ? 3 : (kg == 1) ? 6 : (kg == 2) ? 9 : 11;
  const float* Wc = W2T + o;
  for (int p = pstart; p < pend; p++) {
    int ks = s_off[p], ke = s_off[p + 1];
    float part = 0.0f;
    int k = ks;
    for (; k + 8 <= ke; k += 8) {        // batch 8 independent loads, ordered adds
      int k0 = s_idx[k],     k1 = s_idx[k + 1], k2 = s_idx[k + 2], k3 = s_idx[k + 3];
      int k4 = s_idx[k + 4], k5 = s_idx[k + 5], k6 = s_idx[k + 6], k7 = s_idx[k + 7];
      float w0 = Wc[(size_t)k0 * OUTN];
      float w1 = Wc[(size_t)k1 * OUTN];
      float w2 = Wc[(size_t)k2 * OUTN];
      float w3 = Wc[(size_t)k3 * OUTN];
      float w4 = Wc[(size_t)k4 * OUTN];
      float w5 = Wc[(size_t)k5 * OUTN];
      float w6 = Wc[(size_t)k6 * OUTN];
      float w7 = Wc[(size_t)k7 * OUTN];
      part = __fadd_rn(part, w0);
      part = __fadd_rn(part, w1);
      part = __fadd_rn(part, w2);
      part = __fadd_rn(part, w3);
      part = __fadd_rn(part, w4);
      part = __fadd_rn(part, w5);
      part = __fadd_rn(part, w6);
      part = __fadd_rn(part, w7);
    }
    if (k + 4 <= ke) {
      int k0 = s_idx[k], k1 = s_idx[k + 1], k2 = s_idx[k + 2], k3 = s_idx[k + 3];
      float w0 = Wc[(size_t)k0 * OUTN];
      float w1 = Wc[(size_t)k1 * OUTN];
      float w2 = Wc[(size_t)k2 * OUTN];
      float w3 = Wc[(size_t)k3 * OUTN];
      part = __fadd_rn(part, w0);
      part = __fadd_rn(part, w1);
      part = __fadd_rn(part, w2);
      part = __fadd_rn(part, w3);
      k += 4;
    }
    for (; k < ke; k++) part = __fadd_rn(part, Wc[(size_t)s_idx[k] * OUTN]);
    parts[p][col] = part;
  }
  __syncthreads();

  if (kg == 0) {
    float total = 0.0f;
    #pragma unroll
    for (int p = 0; p < 11; p++) total = __fadd_rn(total, parts[p][col]);
    size_t idx = (size_t)b * OUTN + o;
    float v = v_o[idx], r = r_o[idx];
    unsigned char fired = lif_f32(total, v, r);
    v_o[idx] = v; r_o[idx] = r;
    if (fired) out_acc[idx] = __fadd_rn(out_acc[idx], 1.0f);  // exact int count
  }
}

// ---------------- STDP stats, two-phase (t % 10 == 0) ----------------
// Phase 1: packed byte-lane partial sums over 16-row chunks. Spike bytes are 0/1,
// per-byte totals <= 128 so packed u32 atomicAdd never carries across byte lanes
// -> exact integer column counts. atomicAdd targets are DISTINCT per thread.
#define NWSTAT ((IN + HID) / 4)   // 1280 u32 words
__global__ __launch_bounds__(256) void stats1_k(
    const unsigned char* __restrict__ in_spk, const unsigned char* __restrict__ hid_spk,
    unsigned* __restrict__ pcnt) {
  int w = blockIdx.x * 256 + threadIdx.x;   // word index in [0, NWSTAT)
  int r0 = blockIdx.y * 16;                 // 8 chunks x 16 rows
  unsigned s = 0;
  if (w < IN / 4) {
    const unsigned* p = (const unsigned*)in_spk;
    #pragma unroll
    for (int b = 0; b < 16; b++) s += p[(size_t)(r0 + b) * (IN / 4) + w];
  } else {
    const unsigned* p = (const unsigned*)hid_spk;
    int w2 = w - IN / 4;
    #pragma unroll
    for (int b = 0; b < 16; b++) s += p[(size_t)(r0 + b) * (HID / 4) + w2];
  }
  atomicAdd(pcnt + w, s);
}

// Phase 2: exact counts -> pm, trace updates, flags. Wave ballot + ONE atomic per
// wave (per-thread atomicOr to 2 addresses measured at 59us). Waves never straddle
// the IN boundary (IN = 4 blocks exactly).
__global__ __launch_bounds__(256) void stats2_k(
    const unsigned* __restrict__ pcnt,
    float* __restrict__ pre_m, float* __restrict__ post_m,
    float* __restrict__ tp, float* __restrict__ tn, int* __restrict__ flags) {
  int c = blockIdx.x * 256 + threadIdx.x;   // column in [0, IN+HID)
  int cnt = (int)((pcnt[c >> 2] >> ((c & 3) * 8)) & 0xff);
  int lane = threadIdx.x & 63;
  if (c < IN) {
    float pm = __fdiv_rn((float)cnt, 128.0f);       // exact (pow2)
    pre_m[c] = pm;
    tp[c] = __fadd_rn(__fmul_rn(0.9f, tp[c]), pm);  // tp_n committed (stdp step)
    unsigned long long any = __ballot(cnt > 0);
    if (any && lane == 0) atomicOr(flags + 0, 1);   // one atomic per wave
  } else {
    int h = c - IN;
    float pm = __fdiv_rn((float)cnt, 128.0f);
    post_m[h] = pm;
    tn[h] = __fadd_rn(__fmul_rn(0.9f, tn[h]), pm);
    unsigned long long any = __ballot(cnt > 0);
    if (any && lane == 0) atomicOr(flags + 1, 1);
  }
}

__global__ __launch_bounds__(256) void apply_k(
    float* __restrict__ W1T,
    const float* __restrict__ tp, const float* __restrict__ tn,
    const float* __restrict__ pre_m, const float* __restrict__ post_m,
    const int* __restrict__ flags) {
  if (!(flags[0] && flags[1])) return;   // 'both' gate
  size_t idx = (size_t)blockIdx.x * 256 + threadIdx.x;  // i*HID + h layout
  int i = (int)(idx >> 12);
  int h = (int)(idx & 4095);
  float a  = __fmul_rn(tp[i], post_m[h]);     // tp already == tp_n
  float b2 = __fmul_rn(pre_m[i], tn[h]);      // tn already == tn_n
  float d  = __fmul_rn(0.001f, __fsub_rn(a, b2));
  float w  = __fadd_rn(W1T[idx], d);
  w = fminf(fmaxf(w, -1.0f), 1.0f);           // jnp.clip: max then min
  W1T[idx] = w;
}

__global__ __launch_bounds__(256) void scale_k(const float* __restrict__ acc,
                                               float* __restrict__ out) {
  int j = blockIdx.x * 256 + threadIdx.x;
  out[j] = __fdiv_rn(acc[j], 100.0f);
}

// ---------------- host launcher ----------------
extern "C" void kernel_launch(void* const* d_in, const int* in_sizes, int n_in,
                              void* d_out, int out_size, void* d_ws, size_t ws_size,
                              hipStream_t stream) {
  (void)in_sizes; (void)n_in; (void)out_size; (void)ws_size;
  const float* x     = (const float*)d_in[0];
  const float* W1    = (const float*)d_in[1];
  const float* W2    = (const float*)d_in[2];
  const float* noise = (const float*)d_in[3];

  char* ws = (char*)d_ws;
  size_t off = 0;
  auto alloc = [&](size_t bytes) -> char* {
    char* p = ws + off;
    off += (bytes + 255) & ~(size_t)255;
    return p;
  };
  float* W1T   = (float*)alloc((size_t)IN * HID * 4);     // 16 MB working copy (i-major)
  float* W2T   = (float*)alloc((size_t)HID * OUTN * 4);   // 16 MB (h-major)
  float* v_h   = (float*)alloc((size_t)BB * HID * 4);
  float* r_h   = (float*)alloc((size_t)BB * HID * 4);
  float* v_o   = (float*)alloc((size_t)BB * OUTN * 4);
  float* r_o   = (float*)alloc((size_t)BB * OUTN * 4);
  float* rinA  = (float*)alloc((size_t)BB * IN * 4);      // ping-pong refractory state
  float* rinB  = (float*)alloc((size_t)BB * IN * 4);
  float* acc   = (float*)alloc((size_t)BB * OUTN * 4);
  float* tp    = (float*)alloc((size_t)IN * 4);
  float* tn    = (float*)alloc((size_t)HID * 4);
  float* pre_m = (float*)alloc((size_t)IN * 4);
  float* post_m= (float*)alloc((size_t)HID * 4);
  unsigned char* in_spk  = (unsigned char*)alloc((size_t)BB * IN);
  unsigned char* hid_spk = (unsigned char*)alloc((size_t)BB * HID);
  unsigned* pcnt = (unsigned*)alloc((size_t)10 * NWSTAT * 4);  // per-STDP-step slots
  int* flags   = (int*)alloc(2 * 10 * sizeof(int));            // per-STDP-step slots

  // zero all state (ws is poisoned before every call)
  hipMemsetAsync(v_h, 0, (size_t)BB * HID * 4, stream);
  hipMemsetAsync(r_h, 0, (size_t)BB * HID * 4, stream);
  hipMemsetAsync(v_o, 0, (size_t)BB * OUTN * 4, stream);
  hipMemsetAsync(r_o, 0, (size_t)BB * OUTN * 4, stream);
  hipMemsetAsync(rinA, 0, (size_t)BB * IN * 4, stream);
  hipMemsetAsync(acc, 0, (size_t)BB * OUTN * 4, stream);
  hipMemsetAsync(tp,  0, (size_t)IN * 4, stream);
  hipMemsetAsync(tn,  0, (size_t)HID * 4, stream);
  hipMemsetAsync(pcnt, 0, (size_t)10 * NWSTAT * 4, stream);
  hipMemsetAsync(flags, 0, 2 * 10 * sizeof(int), stream);

  // W1 (HID x IN) -> W1T (IN x HID); W2 (OUTN x HID) -> W2T (HID x OUTN). Tiled.
  ttrans_k<<<dim3(IN / 32, HID / 32), 256, 0, stream>>>(W1, W1T, HID, IN);
  ttrans_k<<<dim3(HID / 32, OUTN / 32), 256, 0, stream>>>(W2, W2T, OUTN, HID);

  float* rin_in = rinA;
  float* rin_out = rinB;
  for (int t = 0; t < TSTEPS; t++) {
    const float* nz = noise + (size_t)t * BB * IN;
    hidden_k<<<dim3(HID / 256, BB), 256, 0, stream>>>(nz, x, rin_in, rin_out, in_spk,
                                                      W1T, v_h, r_h, hid_spk);
    out_k<<<dim3(OUTN / 64, BB), 256, 0, stream>>>(hid_spk, W2T, v_o, r_o, acc);
    if (t % 10 == 0) {
      unsigned* pc = pcnt + (size_t)NWSTAT * (t / 10);
      int* fl = flags + 2 * (t / 10);
      stats1_k<<<dim3(NWSTAT / 256, 8), 256, 0, stream>>>(in_spk, hid_spk, pc);
      stats2_k<<<(IN + HID) / 256, 256, 0, stream>>>(pc, pre_m, post_m, tp, tn, fl);
      apply_k<<<(IN * HID) / 256, 256, 0, stream>>>(W1T, tp, tn, pre_m, post_m, fl);
    }
    float* tmpp = rin_in; rin_in = rin_out; rin_out = tmpp;
  }
  scale_k<<<(BB * OUTN) / 256, 256, 0, stream>>>(acc, (float*)d_out);
}

// Round 7
// 2087.632 us; speedup vs baseline: 2.2963x; 1.0742x over previous
//
#include <hip/hip_runtime.h>
#include <cstdint>
#include <cstddef>

#define BB   128
#define IN   1024
#define HID  4096
#define OUTN 1024
#define TSTEPS 100
#define KC   384   // OpenBLAS SGEMM_DEFAULT_Q — panel structure must be preserved exactly

// ---------------- tiled transpose: dst[c*R + r] = src[r*C + c] ----------------
__global__ __launch_bounds__(256) void ttrans_k(const float* __restrict__ src,
                                                float* __restrict__ dst,
                                                int R, int C) {
  __shared__ float tile[32][33];
  int tx = threadIdx.x & 31;
  int ty = threadIdx.x >> 5;            // 0..7
  int c0 = blockIdx.x * 32, r0 = blockIdx.y * 32;
  #pragma unroll
  for (int j = 0; j < 32; j += 8)
    tile[ty + j][tx] = src[(size_t)(r0 + ty + j) * C + (c0 + tx)];
  __syncthreads();
  #pragma unroll
  for (int j = 0; j < 32; j += 8)
    dst[(size_t)(c0 + ty + j) * R + (r0 + tx)] = tile[tx][ty + j];
}

// f32 LIF exactly mirroring the reference op order (no FMA contraction).
__device__ __forceinline__ unsigned char lif_f32(float I, float& v, float& r) {
  bool active = I > 0.0f;
  bool refrac = r > 0.0f;
  float vi = __fadd_rn(__fmul_rn(v, 0.95f), I);
  bool fired = active && !refrac && (vi >= 1.0f);
  float vn = !active ? v : ((refrac || fired) ? 0.0f : vi);
  float rn = !active ? r : (refrac ? (r - 1.0f) : (fired ? 2.0f : r));
  v = vn; r = rn;
  return fired ? (unsigned char)1 : (unsigned char)0;
}

// ================= hidden role: fused encode + compaction + sparse panel sum =====
// Bit-exactness: within each KC panel the gated ascending-k adds are identical to
// iterating only the spiking k in ascending order; panels combined via one rounded
// add each. Load batching (8/4-wide) does not change the add order.
__device__ __forceinline__ void hidden_body(
    int bx, int b, int tid,
    const float* __restrict__ noise_t, const float* __restrict__ x,
    const float* __restrict__ rin_in, float* __restrict__ rin_out,
    unsigned char* __restrict__ in_spk,
    const float* __restrict__ W1T,
    float* __restrict__ v_h, float* __restrict__ r_h,
    unsigned char* __restrict__ hid_spk,
    unsigned short* s_idx, int* s_off, int* wsum) {
  int h = bx * 256 + tid;

  // ---- fused encode: each thread owns k in [tid*4, tid*4+4) ----
  size_t ebase = (size_t)b * IN + (size_t)tid * 4;
  const float4 xv = *reinterpret_cast<const float4*>(x + ebase);
  const float4 nv = *reinterpret_cast<const float4*>(noise_t + ebase);
  const float4 rv = *reinterpret_cast<const float4*>(rin_in + ebase);
  float px[4] = {xv.x, xv.y, xv.z, xv.w};
  float pn[4] = {nv.x, nv.y, nv.z, nv.w};
  float pr[4] = {rv.x, rv.y, rv.z, rv.w};
  int f[4]; float rn[4];
  #pragma unroll
  for (int j = 0; j < 4; j++) {
    float p = __fmul_rn(px[j], 100.0f);
    p = fminf(fmaxf(p, 0.0f), 100.0f);
    p = __fmul_rn(p, 0.001f);
    bool s = pn[j] < p;                  // Bernoulli encode (strict <)
    bool refrac = pr[j] > 0.0f;
    bool fired = s && !refrac;           // input-layer v == 0 always (proven)
    rn[j] = !s ? pr[j] : (refrac ? (pr[j] - 1.0f) : 2.0f);
    f[j] = fired ? 1 : 0;
  }
  if (bx == 0) {                         // single owner commits state
    *reinterpret_cast<float4*>(rin_out + ebase) = make_float4(rn[0], rn[1], rn[2], rn[3]);
    uchar4 sp; sp.x = (unsigned char)f[0]; sp.y = (unsigned char)f[1];
    sp.z = (unsigned char)f[2]; sp.w = (unsigned char)f[3];
    *reinterpret_cast<uchar4*>(in_spk + ebase) = sp;
  }
  int cnt = f[0] + f[1] + f[2] + f[3];

  // ---- block exclusive scan: wave-inclusive shfl scan + cross-wave combine ----
  int lane = tid & 63, wv = tid >> 6;
  int inc = cnt;
  #pragma unroll
  for (int d = 1; d < 64; d <<= 1) {
    int nn = __shfl_up(inc, d, 64);
    if (lane >= d) inc += nn;
  }
  if (lane == 63) wsum[wv] = inc;
  __syncthreads();
  int wbase = 0;
  #pragma unroll
  for (int w = 0; w < 4; w++) if (w < wv) wbase += wsum[w];
  int excl = wbase + inc - cnt;

  int o = excl, kb = tid * 4;
  if (f[0]) s_idx[o++] = (unsigned short)(kb);
  if (f[1]) s_idx[o++] = (unsigned short)(kb + 1);
  if (f[2]) s_idx[o++] = (unsigned short)(kb + 2);
  if (f[3]) s_idx[o++] = (unsigned short)(kb + 3);
  if (tid == 0)   s_off[0] = 0;          // panel k=0    starts at thread 0
  if (tid == 96)  s_off[1] = excl;       // panel k=384  starts at thread 96
  if (tid == 192) s_off[2] = excl;       // panel k=768  starts at thread 192
  if (tid == 255) s_off[3] = excl + cnt; // total spike count
  __syncthreads();

  float total = 0.0f;
  const float* Wc = W1T + h;
  #pragma unroll
  for (int p = 0; p < 3; p++) {
    int ks = s_off[p], ke = s_off[p + 1];
    float part = 0.0f;
    int k = ks;
    for (; k + 8 <= ke; k += 8) {        // batch 8 independent loads, ordered adds
      int k0 = s_idx[k],     k1 = s_idx[k + 1], k2 = s_idx[k + 2], k3 = s_idx[k + 3];
      int k4 = s_idx[k + 4], k5 = s_idx[k + 5], k6 = s_idx[k + 6], k7 = s_idx[k + 7];
      float w0 = Wc[(size_t)k0 * HID];
      float w1 = Wc[(size_t)k1 * HID];
      float w2 = Wc[(size_t)k2 * HID];
      float w3 = Wc[(size_t)k3 * HID];
      float w4 = Wc[(size_t)k4 * HID];
      float w5 = Wc[(size_t)k5 * HID];
      float w6 = Wc[(size_t)k6 * HID];
      float w7 = Wc[(size_t)k7 * HID];
      part = __fadd_rn(part, w0);
      part = __fadd_rn(part, w1);
      part = __fadd_rn(part, w2);
      part = __fadd_rn(part, w3);
      part = __fadd_rn(part, w4);
      part = __fadd_rn(part, w5);
      part = __fadd_rn(part, w6);
      part = __fadd_rn(part, w7);
    }
    if (k + 4 <= ke) {
      int k0 = s_idx[k], k1 = s_idx[k + 1], k2 = s_idx[k + 2], k3 = s_idx[k + 3];
      float w0 = Wc[(size_t)k0 * HID];
      float w1 = Wc[(size_t)k1 * HID];
      float w2 = Wc[(size_t)k2 * HID];
      float w3 = Wc[(size_t)k3 * HID];
      part = __fadd_rn(part, w0);
      part = __fadd_rn(part, w1);
      part = __fadd_rn(part, w2);
      part = __fadd_rn(part, w3);
      k += 4;
    }
    for (; k < ke; k++) part = __fadd_rn(part, Wc[(size_t)s_idx[k] * HID]);
    total = __fadd_rn(total, part);      // first panel: rn(0+P0)=P0 exact
  }
  size_t idx = (size_t)b * HID + h;
  float v = v_h[idx], r = r_h[idx];
  hid_spk[idx] = lif_f32(total, v, r);
  v_h[idx] = v; r_h[idx] = r;
}

// ================= out role: wave-split panels + compaction + LIF ================
// Block covers 64 output columns; 11 KC panels split across 4 waves into LDS
// parts[11][64]; wave 0 does the ordered 11-add left-fold + LIF (bit-identical).
__device__ __forceinline__ void out_body(
    int bx, int b, int tid,
    const unsigned char* __restrict__ hid_spk,
    const float* __restrict__ W2T,
    float* __restrict__ v_o, float* __restrict__ r_o,
    float* __restrict__ out_acc,
    unsigned short* s_idx, int* s_off, int* wsum, float* parts) {
  int col = tid & 63;                    // output column within block
  int kg  = tid >> 6;                    // wave id = panel group
  int o = bx * 64 + col;

  // each thread owns k in [tid*16, tid*16+16)
  uint4 u = *reinterpret_cast<const uint4*>(hid_spk + (size_t)b * HID + tid * 16);
  unsigned ww[4] = {u.x, u.y, u.z, u.w};
  int cnt = 0;
  #pragma unroll
  for (int j = 0; j < 16; j++) cnt += (ww[j >> 2] >> ((j & 3) * 8)) & 0xff;

  int lane = tid & 63, wv = tid >> 6;
  int inc = cnt;
  #pragma unroll
  for (int d = 1; d < 64; d <<= 1) {
    int nn = __shfl_up(inc, d, 64);
    if (lane >= d) inc += nn;
  }
  if (lane == 63) wsum[wv] = inc;
  __syncthreads();
  int wbase = 0;
  #pragma unroll
  for (int w = 0; w < 4; w++) if (w < wv) wbase += wsum[w];
  int excl = wbase + inc - cnt;

  int oo = excl, kb = tid * 16;
  #pragma unroll
  for (int j = 0; j < 16; j++) {
    if ((ww[j >> 2] >> ((j & 3) * 8)) & 0xff) s_idx[oo++] = (unsigned short)(kb + j);
  }
  // panel p starts at k = 384*p -> thread 24*p (384/16 == 24, exact)
  if ((tid % 24) == 0 && tid <= 240) s_off[tid / 24] = excl;
  if (tid == 255) s_off[11] = excl + cnt;
  __syncthreads();

  const int pstart = (kg == 0) ? 0 : (kg == 1) ? 3 : (kg == 2) ? 6 : 9;
  const int pend   = (kg == 0) ? 3 : (kg == 1) ? 6 : (kg == 2) ? 9 : 11;
  const float* Wc = W2T + o;
  for (int p = pstart; p < pend; p++) {
    int ks = s_off[p], ke = s_off[p + 1];
    float part = 0.0f;
    int k = ks;
    for (; k + 8 <= ke; k += 8) {        // batch 8 independent loads, ordered adds
      int k0 = s_idx[k],     k1 = s_idx[k + 1], k2 = s_idx[k + 2], k3 = s_idx[k + 3];
      int k4 = s_idx[k + 4], k5 = s_idx[k + 5], k6 = s_idx[k + 6], k7 = s_idx[k + 7];
      float w0 = Wc[(size_t)k0 * OUTN];
      float w1 = Wc[(size_t)k1 * OUTN];
      float w2 = Wc[(size_t)k2 * OUTN];
      float w3 = Wc[(size_t)k3 * OUTN];
      float w4 = Wc[(size_t)k4 * OUTN];
      float w5 = Wc[(size_t)k5 * OUTN];
      float w6 = Wc[(size_t)k6 * OUTN];
      float w7 = Wc[(size_t)k7 * OUTN];
      part = __fadd_rn(part, w0);
      part = __fadd_rn(part, w1);
      part = __fadd_rn(part, w2);
      part = __fadd_rn(part, w3);
      part = __fadd_rn(part, w4);
      part = __fadd_rn(part, w5);
      part = __fadd_rn(part, w6);
      part = __fadd_rn(part, w7);
    }
    if (k + 4 <= ke) {
      int k0 = s_idx[k], k1 = s_idx[k + 1], k2 = s_idx[k + 2], k3 = s_idx[k + 3];
      float w0 = Wc[(size_t)k0 * OUTN];
      float w1 = Wc[(size_t)k1 * OUTN];
      float w2 = Wc[(size_t)k2 * OUTN];
      float w3 = Wc[(size_t)k3 * OUTN];
      part = __fadd_rn(part, w0);
      part = __fadd_rn(part, w1);
      part = __fadd_rn(part, w2);
      part = __fadd_rn(part, w3);
      k += 4;
    }
    for (; k < ke; k++) part = __fadd_rn(part, Wc[(size_t)s_idx[k] * OUTN]);
    parts[p * 64 + col] = part;
  }
  __syncthreads();

  if (kg == 0) {
    float total = 0.0f;
    #pragma unroll
    for (int p = 0; p < 11; p++) total = __fadd_rn(total, parts[p * 64 + col]);
    size_t idx = (size_t)b * OUTN + o;
    float v = v_o[idx], r = r_o[idx];
    unsigned char fired = lif_f32(total, v, r);
    v_o[idx] = v; r_o[idx] = r;
    if (fired) out_acc[idx] = __fadd_rn(out_acc[idx], 1.0f);  // exact int count
  }
}

// ---------------- standalone boundary kernels ----------------
__global__ __launch_bounds__(256) void hidden_k(
    const float* __restrict__ noise_t, const float* __restrict__ x,
    const float* __restrict__ rin_in, float* __restrict__ rin_out,
    unsigned char* __restrict__ in_spk,
    const float* __restrict__ W1T,
    float* __restrict__ v_h, float* __restrict__ r_h,
    unsigned char* __restrict__ hid_spk) {
  __shared__ unsigned short s_idx[IN];
  __shared__ int s_off[4];
  __shared__ int wsum[4];
  hidden_body(blockIdx.x, blockIdx.y, threadIdx.x, noise_t, x, rin_in, rin_out,
              in_spk, W1T, v_h, r_h, hid_spk, s_idx, s_off, wsum);
}

__global__ __launch_bounds__(256) void out_k(
    const unsigned char* __restrict__ hid_spk, const float* __restrict__ W2T,
    float* __restrict__ v_o, float* __restrict__ r_o, float* __restrict__ out_acc) {
  __shared__ unsigned short s_idx[HID];
  __shared__ int s_off[12];
  __shared__ int wsum[4];
  __shared__ float parts[11 * 64];
  out_body(blockIdx.x, blockIdx.y, threadIdx.x, hid_spk, W2T, v_o, r_o, out_acc,
           s_idx, s_off, wsum, parts);
}

// ---------------- merged step: out(t-1) || hidden(t) in one launch ---------------
// Roles are data-independent: out reads hid_spk_r (written last launch), hidden
// writes hid_spk_w (ping-pong buffer). Shared memory is a union (max 11072 B).
__global__ __launch_bounds__(256) void step_k(
    const float* __restrict__ noise_t, const float* __restrict__ x,
    const float* __restrict__ rin_in, float* __restrict__ rin_out,
    unsigned char* __restrict__ in_spk,
    const float* __restrict__ W1T,
    float* __restrict__ v_h, float* __restrict__ r_h,
    unsigned char* __restrict__ hid_spk_w,
    const unsigned char* __restrict__ hid_spk_r,
    const float* __restrict__ W2T,
    float* __restrict__ v_o, float* __restrict__ r_o, float* __restrict__ out_acc) {
  __shared__ __align__(16) unsigned char smem[11072];
  int b = blockIdx.y;
  if (blockIdx.x < 16) {
    unsigned short* s_idx = (unsigned short*)smem;              // 2048 B
    int* s_off = (int*)(smem + 2048);                            // 16 B
    int* wsum  = (int*)(smem + 2064);                            // 16 B
    hidden_body(blockIdx.x, b, threadIdx.x, noise_t, x, rin_in, rin_out,
                in_spk, W1T, v_h, r_h, hid_spk_w, s_idx, s_off, wsum);
  } else {
    unsigned short* s_idx = (unsigned short*)smem;              // 8192 B
    int* s_off = (int*)(smem + 8192);                            // 48 B
    int* wsum  = (int*)(smem + 8240);                            // 16 B
    float* parts = (float*)(smem + 8256);                        // 2816 B
    out_body(blockIdx.x - 16, b, threadIdx.x, hid_spk_r, W2T, v_o, r_o, out_acc,
             s_idx, s_off, wsum, parts);
  }
}

// ---------------- STDP stats, two-phase (t % 10 == 0) ----------------
// Phase 1: packed byte-lane partial sums over 16-row chunks (bytes are 0/1, totals
// <= 128: no cross-byte carry -> exact counts). atomicAdd targets distinct/thread.
#define NWSTAT ((IN + HID) / 4)   // 1280 u32 words
__global__ __launch_bounds__(256) void stats1_k(
    const unsigned char* __restrict__ in_spk, const unsigned char* __restrict__ hid_spk,
    unsigned* __restrict__ pcnt) {
  int w = blockIdx.x * 256 + threadIdx.x;   // word index in [0, NWSTAT)
  int r0 = blockIdx.y * 16;                 // 8 chunks x 16 rows
  unsigned s = 0;
  if (w < IN / 4) {
    const unsigned* p = (const unsigned*)in_spk;
    #pragma unroll
    for (int b = 0; b < 16; b++) s += p[(size_t)(r0 + b) * (IN / 4) + w];
  } else {
    const unsigned* p = (const unsigned*)hid_spk;
    int w2 = w - IN / 4;
    #pragma unroll
    for (int b = 0; b < 16; b++) s += p[(size_t)(r0 + b) * (HID / 4) + w2];
  }
  atomicAdd(pcnt + w, s);
}

// Phase 2: counts -> pm, trace updates, flags. Wave ballot + ONE atomic per wave.
__global__ __launch_bounds__(256) void stats2_k(
    const unsigned* __restrict__ pcnt,
    float* __restrict__ pre_m, float* __restrict__ post_m,
    float* __restrict__ tp, float* __restrict__ tn, int* __restrict__ flags) {
  int c = blockIdx.x * 256 + threadIdx.x;   // column in [0, IN+HID)
  int cnt = (int)((pcnt[c >> 2] >> ((c & 3) * 8)) & 0xff);
  int lane = threadIdx.x & 63;
  if (c < IN) {
    float pm = __fdiv_rn((float)cnt, 128.0f);       // exact (pow2)
    pre_m[c] = pm;
    tp[c] = __fadd_rn(__fmul_rn(0.9f, tp[c]), pm);  // tp_n committed (stdp step)
    unsigned long long any = __ballot(cnt > 0);
    if (any && lane == 0) atomicOr(flags + 0, 1);   // one atomic per wave
  } else {
    int h = c - IN;
    float pm = __fdiv_rn((float)cnt, 128.0f);
    post_m[h] = pm;
    tn[h] = __fadd_rn(__fmul_rn(0.9f, tn[h]), pm);
    unsigned long long any = __ballot(cnt > 0);
    if (any && lane == 0) atomicOr(flags + 1, 1);
  }
}

__global__ __launch_bounds__(256) void apply_k(
    float* __restrict__ W1T,
    const float* __restrict__ tp, const float* __restrict__ tn,
    const float* __restrict__ pre_m, const float* __restrict__ post_m,
    const int* __restrict__ flags) {
  if (!(flags[0] && flags[1])) return;   // 'both' gate
  size_t idx = (size_t)blockIdx.x * 256 + threadIdx.x;  // i*HID + h layout
  int i = (int)(idx >> 12);
  int h = (int)(idx & 4095);
  float a  = __fmul_rn(tp[i], post_m[h]);     // tp already == tp_n
  float b2 = __fmul_rn(pre_m[i], tn[h]);      // tn already == tn_n
  float d  = __fmul_rn(0.001f, __fsub_rn(a, b2));
  float w  = __fadd_rn(W1T[idx], d);
  w = fminf(fmaxf(w, -1.0f), 1.0f);           // jnp.clip: max then min
  W1T[idx] = w;
}

__global__ __launch_bounds__(256) void scale_k(const float* __restrict__ acc,
                                               float* __restrict__ out) {
  int j = blockIdx.x * 256 + threadIdx.x;
  out[j] = __fdiv_rn(acc[j], 100.0f);
}

// ---------------- host launcher ----------------
extern "C" void kernel_launch(void* const* d_in, const int* in_sizes, int n_in,
                              void* d_out, int out_size, void* d_ws, size_t ws_size,
                              hipStream_t stream) {
  (void)in_sizes; (void)n_in; (void)out_size; (void)ws_size;
  const float* x     = (const float*)d_in[0];
  const float* W1    = (const float*)d_in[1];
  const float* W2    = (const float*)d_in[2];
  const float* noise = (const float*)d_in[3];

  char* ws = (char*)d_ws;
  size_t off = 0;
  auto alloc = [&](size_t bytes) -> char* {
    char* p = ws + off;
    off += (bytes + 255) & ~(size_t)255;
    return p;
  };
  float* W1T   = (float*)alloc((size_t)IN * HID * 4);     // 16 MB working copy (i-major)
  float* W2T   = (float*)alloc((size_t)HID * OUTN * 4);   // 16 MB (h-major)
  float* v_h   = (float*)alloc((size_t)BB * HID * 4);
  float* r_h   = (float*)alloc((size_t)BB * HID * 4);
  float* v_o   = (float*)alloc((size_t)BB * OUTN * 4);
  float* r_o   = (float*)alloc((size_t)BB * OUTN * 4);
  float* rinA  = (float*)alloc((size_t)BB * IN * 4);      // ping-pong refractory state
  float* rinB  = (float*)alloc((size_t)BB * IN * 4);
  float* acc   = (float*)alloc((size_t)BB * OUTN * 4);
  float* tp    = (float*)alloc((size_t)IN * 4);
  float* tn    = (float*)alloc((size_t)HID * 4);
  float* pre_m = (float*)alloc((size_t)IN * 4);
  float* post_m= (float*)alloc((size_t)HID * 4);
  unsigned char* in_spk   = (unsigned char*)alloc((size_t)BB * IN);
  unsigned char* hid_spkA = (unsigned char*)alloc((size_t)BB * HID);  // ping-pong
  unsigned char* hid_spkB = (unsigned char*)alloc((size_t)BB * HID);
  unsigned* pcnt = (unsigned*)alloc((size_t)10 * NWSTAT * 4);  // per-STDP-step slots
  int* flags   = (int*)alloc(2 * 10 * sizeof(int));            // per-STDP-step slots

  // zero all state (ws is poisoned before every call)
  hipMemsetAsync(v_h, 0, (size_t)BB * HID * 4, stream);
  hipMemsetAsync(r_h, 0, (size_t)BB * HID * 4, stream);
  hipMemsetAsync(v_o, 0, (size_t)BB * OUTN * 4, stream);
  hipMemsetAsync(r_o, 0, (size_t)BB * OUTN * 4, stream);
  hipMemsetAsync(rinA, 0, (size_t)BB * IN * 4, stream);
  hipMemsetAsync(acc, 0, (size_t)BB * OUTN * 4, stream);
  hipMemsetAsync(tp,  0, (size_t)IN * 4, stream);
  hipMemsetAsync(tn,  0, (size_t)HID * 4, stream);
  hipMemsetAsync(pcnt, 0, (size_t)10 * NWSTAT * 4, stream);
  hipMemsetAsync(flags, 0, 2 * 10 * sizeof(int), stream);

  // W1 (HID x IN) -> W1T (IN x HID); W2 (OUTN x HID) -> W2T (HID x OUTN). Tiled.
  ttrans_k<<<dim3(IN / 32, HID / 32), 256, 0, stream>>>(W1, W1T, HID, IN);
  ttrans_k<<<dim3(HID / 32, OUTN / 32), 256, 0, stream>>>(W2, W2T, OUTN, HID);

  float* rin_in = rinA;
  float* rin_out = rinB;

  // t = 0: hidden only
  hidden_k<<<dim3(HID / 256, BB), 256, 0, stream>>>(noise, x, rin_in, rin_out, in_spk,
                                                    W1T, v_h, r_h, hid_spkA);
  {
    unsigned* pc = pcnt;  int* fl = flags;
    stats1_k<<<dim3(NWSTAT / 256, 8), 256, 0, stream>>>(in_spk, hid_spkA, pc);
    stats2_k<<<(IN + HID) / 256, 256, 0, stream>>>(pc, pre_m, post_m, tp, tn, fl);
    apply_k<<<(IN * HID) / 256, 256, 0, stream>>>(W1T, tp, tn, pre_m, post_m, fl);
  }
  { float* tmpp = rin_in; rin_in = rin_out; rin_out = tmpp; }

  // t = 1..99: merged out(t-1) || hidden(t)
  for (int t = 1; t < TSTEPS; t++) {
    const float* nz = noise + (size_t)t * BB * IN;
    unsigned char* hs_w = (t & 1) ? hid_spkB : hid_spkA;
    unsigned char* hs_r = (t & 1) ? hid_spkA : hid_spkB;
    step_k<<<dim3(32, BB), 256, 0, stream>>>(nz, x, rin_in, rin_out, in_spk,
                                             W1T, v_h, r_h, hs_w, hs_r,
                                             W2T, v_o, r_o, acc);
    if (t % 10 == 0) {
      unsigned* pc = pcnt + (size_t)NWSTAT * (t / 10);
      int* fl = flags + 2 * (t / 10);
      stats1_k<<<dim3(NWSTAT / 256, 8), 256, 0, stream>>>(in_spk, hs_w, pc);
      stats2_k<<<(IN + HID) / 256, 256, 0, stream>>>(pc, pre_m, post_m, tp, tn, fl);
      apply_k<<<(IN * HID) / 256, 256, 0, stream>>>(W1T, tp, tn, pre_m, post_m, fl);
    }
    float* tmpp = rin_in; rin_in = rin_out; rin_out = tmpp;
  }

  // final: out(99)
  unsigned char* hs_last = ((TSTEPS - 1) & 1) ? hid_spkB : hid_spkA;
  out_k<<<dim3(OUTN / 64, BB), 256, 0, stream>>>(hs_last, W2T, v_o, r_o, acc);

  scale_k<<<(BB * OUTN) / 256, 256, 0, stream>>>(acc, (float*)d_out);
}

// Round 8
// 1500.745 us; speedup vs baseline: 3.1942x; 1.3911x over previous
//
#include <hip/hip_runtime.h>
#include <cstdint>
#include <cstddef>

#define BB   128
#define IN   1024
#define HID  4096
#define OUTN 1024
#define TSTEPS 100
#define KC   384   // OpenBLAS SGEMM_DEFAULT_Q — panel structure must be preserved exactly

// ---------------- tiled transpose: dst[c*R + r] = src[r*C + c] ----------------
__global__ __launch_bounds__(256) void ttrans_k(const float* __restrict__ src,
                                                float* __restrict__ dst,
                                                int R, int C) {
  __shared__ float tile[32][33];
  int tx = threadIdx.x & 31;
  int ty = threadIdx.x >> 5;            // 0..7
  int c0 = blockIdx.x * 32, r0 = blockIdx.y * 32;
  #pragma unroll
  for (int j = 0; j < 32; j += 8)
    tile[ty + j][tx] = src[(size_t)(r0 + ty + j) * C + (c0 + tx)];
  __syncthreads();
  #pragma unroll
  for (int j = 0; j < 32; j += 8)
    dst[(size_t)(c0 + ty + j) * R + (r0 + tx)] = tile[tx][ty + j];
}

// f32 LIF exactly mirroring the reference op order (no FMA contraction).
__device__ __forceinline__ unsigned char lif_f32(float I, float& v, float& r) {
  bool active = I > 0.0f;
  bool refrac = r > 0.0f;
  float vi = __fadd_rn(__fmul_rn(v, 0.95f), I);
  bool fired = active && !refrac && (vi >= 1.0f);
  float vn = !active ? v : ((refrac || fired) ? 0.0f : vi);
  float rn = !active ? r : (refrac ? (r - 1.0f) : (fired ? 2.0f : r));
  v = vn; r = rn;
  return fired ? (unsigned char)1 : (unsigned char)0;
}

// ================= hidden role: fused encode + compaction + sparse panel sum =====
// Thread owns 4 consecutive h columns; weights loaded as float4 (one 32-bit
// offset (k<<14)+h0*4 from the uniform W1T base). Each column's accumulator chain
// remains ascending-k within each KC panel; panels combined via one rounded add
// each -> bit-identical to the gated-scan original.
__device__ __forceinline__ void hidden_body(
    int bx, int b, int tid,
    const float* __restrict__ noise_t, const float* __restrict__ x,
    const float* __restrict__ rin_in, float* __restrict__ rin_out,
    unsigned char* __restrict__ in_spk,
    const float* __restrict__ W1T,
    float* __restrict__ v_h, float* __restrict__ r_h,
    unsigned char* __restrict__ hid_spk,
    unsigned short* s_idx, int* s_off, int* wsum) {
  // ---- fused encode: each thread owns k in [tid*4, tid*4+4) ----
  size_t ebase = (size_t)b * IN + (size_t)tid * 4;
  const float4 xv = *reinterpret_cast<const float4*>(x + ebase);
  const float4 nv = *reinterpret_cast<const float4*>(noise_t + ebase);
  const float4 rv = *reinterpret_cast<const float4*>(rin_in + ebase);
  float px[4] = {xv.x, xv.y, xv.z, xv.w};
  float pn[4] = {nv.x, nv.y, nv.z, nv.w};
  float pr[4] = {rv.x, rv.y, rv.z, rv.w};
  int f[4]; float rn[4];
  #pragma unroll
  for (int j = 0; j < 4; j++) {
    float p = __fmul_rn(px[j], 100.0f);
    p = fminf(fmaxf(p, 0.0f), 100.0f);
    p = __fmul_rn(p, 0.001f);
    bool s = pn[j] < p;                  // Bernoulli encode (strict <)
    bool refrac = pr[j] > 0.0f;
    bool fired = s && !refrac;           // input-layer v == 0 always (proven)
    rn[j] = !s ? pr[j] : (refrac ? (pr[j] - 1.0f) : 2.0f);
    f[j] = fired ? 1 : 0;
  }
  if (bx == 0) {                         // single owner commits state
    *reinterpret_cast<float4*>(rin_out + ebase) = make_float4(rn[0], rn[1], rn[2], rn[3]);
    uchar4 sp; sp.x = (unsigned char)f[0]; sp.y = (unsigned char)f[1];
    sp.z = (unsigned char)f[2]; sp.w = (unsigned char)f[3];
    *reinterpret_cast<uchar4*>(in_spk + ebase) = sp;
  }
  int cnt = f[0] + f[1] + f[2] + f[3];

  // ---- block exclusive scan: wave-inclusive shfl scan + cross-wave combine ----
  int lane = tid & 63, wv = tid >> 6;
  int inc = cnt;
  #pragma unroll
  for (int d = 1; d < 64; d <<= 1) {
    int nn = __shfl_up(inc, d, 64);
    if (lane >= d) inc += nn;
  }
  if (lane == 63) wsum[wv] = inc;
  __syncthreads();
  int wbase = 0;
  #pragma unroll
  for (int w = 0; w < 4; w++) if (w < wv) wbase += wsum[w];
  int excl = wbase + inc - cnt;

  int o = excl, kb = tid * 4;
  if (f[0]) s_idx[o++] = (unsigned short)(kb);
  if (f[1]) s_idx[o++] = (unsigned short)(kb + 1);
  if (f[2]) s_idx[o++] = (unsigned short)(kb + 2);
  if (f[3]) s_idx[o++] = (unsigned short)(kb + 3);
  if (tid == 0)   s_off[0] = 0;          // panel k=0    starts at thread 0
  if (tid == 96)  s_off[1] = excl;       // panel k=384  starts at thread 96
  if (tid == 192) s_off[2] = excl;       // panel k=768  starts at thread 192
  if (tid == 255) s_off[3] = excl + cnt; // total spike count
  __syncthreads();

  // ---- gather: thread owns h0..h0+3; offsets are 32-bit from uniform base ----
  int h0 = bx * 1024 + tid * 4;
  const char* Wb = (const char*)W1T;
  unsigned cb = (unsigned)h0 << 2;       // column byte offset
  float t0 = 0.0f, t1 = 0.0f, t2 = 0.0f, t3 = 0.0f;
  #pragma unroll
  for (int p = 0; p < 3; p++) {
    int ks = s_off[p], ke = s_off[p + 1];
    float a0 = 0.0f, a1 = 0.0f, a2 = 0.0f, a3 = 0.0f;
    int k = ks;
    for (; k + 4 <= ke; k += 4) {        // batch 4 dwordx4 loads, ordered adds/col
      unsigned o0 = ((unsigned)s_idx[k]     << 14) + cb;   // k*HID*4
      unsigned o1 = ((unsigned)s_idx[k + 1] << 14) + cb;
      unsigned o2 = ((unsigned)s_idx[k + 2] << 14) + cb;
      unsigned o3 = ((unsigned)s_idx[k + 3] << 14) + cb;
      float4 w0 = *reinterpret_cast<const float4*>(Wb + o0);
      float4 w1 = *reinterpret_cast<const float4*>(Wb + o1);
      float4 w2 = *reinterpret_cast<const float4*>(Wb + o2);
      float4 w3 = *reinterpret_cast<const float4*>(Wb + o3);
      a0 = __fadd_rn(a0, w0.x); a1 = __fadd_rn(a1, w0.y);
      a2 = __fadd_rn(a2, w0.z); a3 = __fadd_rn(a3, w0.w);
      a0 = __fadd_rn(a0, w1.x); a1 = __fadd_rn(a1, w1.y);
      a2 = __fadd_rn(a2, w1.z); a3 = __fadd_rn(a3, w1.w);
      a0 = __fadd_rn(a0, w2.x); a1 = __fadd_rn(a1, w2.y);
      a2 = __fadd_rn(a2, w2.z); a3 = __fadd_rn(a3, w2.w);
      a0 = __fadd_rn(a0, w3.x); a1 = __fadd_rn(a1, w3.y);
      a2 = __fadd_rn(a2, w3.z); a3 = __fadd_rn(a3, w3.w);
    }
    for (; k < ke; k++) {
      unsigned oo = ((unsigned)s_idx[k] << 14) + cb;
      float4 w = *reinterpret_cast<const float4*>(Wb + oo);
      a0 = __fadd_rn(a0, w.x); a1 = __fadd_rn(a1, w.y);
      a2 = __fadd_rn(a2, w.z); a3 = __fadd_rn(a3, w.w);
    }
    t0 = __fadd_rn(t0, a0); t1 = __fadd_rn(t1, a1);   // rn(0+P0)=P0 exact
    t2 = __fadd_rn(t2, a2); t3 = __fadd_rn(t3, a3);
  }
  size_t idx = (size_t)b * HID + h0;
  float4 vv = *reinterpret_cast<float4*>(v_h + idx);
  float4 rr = *reinterpret_cast<float4*>(r_h + idx);
  uchar4 sp;
  sp.x = lif_f32(t0, vv.x, rr.x);
  sp.y = lif_f32(t1, vv.y, rr.y);
  sp.z = lif_f32(t2, vv.z, rr.z);
  sp.w = lif_f32(t3, vv.w, rr.w);
  *reinterpret_cast<float4*>(v_h + idx) = vv;
  *reinterpret_cast<float4*>(r_h + idx) = rr;
  *reinterpret_cast<uchar4*>(hid_spk + idx) = sp;
}

// ================= out role: wave-split panels, 4 cols/thread, fold + LIF ========
// Block covers 256 output columns; 11 KC panels split across the 4 waves into
// LDS parts[11][256]; then each thread folds ONE column with the ordered 11-add
// left-fold + LIF (bit-identical).
__device__ __forceinline__ void out_body(
    int bx, int b, int tid,
    const unsigned char* __restrict__ hid_spk,
    const float* __restrict__ W2T,
    float* __restrict__ v_o, float* __restrict__ r_o,
    float* __restrict__ out_acc,
    unsigned short* s_idx, int* s_off, int* wsum, float* parts) {
  int lane = tid & 63, kg = tid >> 6;

  // each thread owns k in [tid*16, tid*16+16)
  uint4 u = *reinterpret_cast<const uint4*>(hid_spk + (size_t)b * HID + tid * 16);
  unsigned ww[4] = {u.x, u.y, u.z, u.w};
  int cnt = 0;
  #pragma unroll
  for (int j = 0; j < 16; j++) cnt += (ww[j >> 2] >> ((j & 3) * 8)) & 0xff;

  int inc = cnt;
  #pragma unroll
  for (int d = 1; d < 64; d <<= 1) {
    int nn = __shfl_up(inc, d, 64);
    if (lane >= d) inc += nn;
  }
  if (lane == 63) wsum[kg] = inc;
  __syncthreads();
  int wbase = 0;
  #pragma unroll
  for (int w = 0; w < 4; w++) if (w < kg) wbase += wsum[w];
  int excl = wbase + inc - cnt;

  int oo = excl, kb = tid * 16;
  #pragma unroll
  for (int j = 0; j < 16; j++) {
    if ((ww[j >> 2] >> ((j & 3) * 8)) & 0xff) s_idx[oo++] = (unsigned short)(kb + j);
  }
  // panel p starts at k = 384*p -> thread 24*p (384/16 == 24, exact)
  if ((tid % 24) == 0 && tid <= 240) s_off[tid / 24] = excl;
  if (tid == 255) s_off[11] = excl + cnt;
  __syncthreads();

  // ---- wave kg computes its panels for cols [bx*256 + lane*4 .. +4) ----
  const int pstart = (kg == 0) ? 0 : (kg == 1) ? 3 : (kg == 2) ? 6 : 9;
  const int pend   = (kg == 0) ? 3 : (kg == 1) ? 6 : (kg == 2) ? 9 : 11;
  int col0 = lane * 4;                   // within-block column
  const char* Wb = (const char*)W2T;
  unsigned cb = ((unsigned)(bx * 256 + col0)) << 2;
  for (int p = pstart; p < pend; p++) {
    int ks = s_off[p], ke = s_off[p + 1];
    float a0 = 0.0f, a1 = 0.0f, a2 = 0.0f, a3 = 0.0f;
    int k = ks;
    for (; k + 4 <= ke; k += 4) {
      unsigned o0 = ((unsigned)s_idx[k]     << 12) + cb;   // k*OUTN*4
      unsigned o1 = ((unsigned)s_idx[k + 1] << 12) + cb;
      unsigned o2 = ((unsigned)s_idx[k + 2] << 12) + cb;
      unsigned o3 = ((unsigned)s_idx[k + 3] << 12) + cb;
      float4 w0 = *reinterpret_cast<const float4*>(Wb + o0);
      float4 w1 = *reinterpret_cast<const float4*>(Wb + o1);
      float4 w2 = *reinterpret_cast<const float4*>(Wb + o2);
      float4 w3 = *reinterpret_cast<const float4*>(Wb + o3);
      a0 = __fadd_rn(a0, w0.x); a1 = __fadd_rn(a1, w0.y);
      a2 = __fadd_rn(a2, w0.z); a3 = __fadd_rn(a3, w0.w);
      a0 = __fadd_rn(a0, w1.x); a1 = __fadd_rn(a1, w1.y);
      a2 = __fadd_rn(a2, w1.z); a3 = __fadd_rn(a3, w1.w);
      a0 = __fadd_rn(a0, w2.x); a1 = __fadd_rn(a1, w2.y);
      a2 = __fadd_rn(a2, w2.z); a3 = __fadd_rn(a3, w2.w);
      a0 = __fadd_rn(a0, w3.x); a1 = __fadd_rn(a1, w3.y);
      a2 = __fadd_rn(a2, w3.z); a3 = __fadd_rn(a3, w3.w);
    }
    for (; k < ke; k++) {
      unsigned ob = ((unsigned)s_idx[k] << 12) + cb;
      float4 w = *reinterpret_cast<const float4*>(Wb + ob);
      a0 = __fadd_rn(a0, w.x); a1 = __fadd_rn(a1, w.y);
      a2 = __fadd_rn(a2, w.z); a3 = __fadd_rn(a3, w.w);
    }
    *reinterpret_cast<float4*>(parts + p * 256 + col0) = make_float4(a0, a1, a2, a3);
  }
  __syncthreads();

  // ---- each thread folds one column (ordered 11-add left-fold) + LIF ----
  float total = 0.0f;
  #pragma unroll
  for (int p = 0; p < 11; p++) total = __fadd_rn(total, parts[p * 256 + tid]);
  int o = bx * 256 + tid;
  size_t idx = (size_t)b * OUTN + o;
  float v = v_o[idx], r = r_o[idx];
  unsigned char fired = lif_f32(total, v, r);
  v_o[idx] = v; r_o[idx] = r;
  if (fired) out_acc[idx] = __fadd_rn(out_acc[idx], 1.0f);  // exact int count
}

// ---------------- standalone boundary kernels ----------------
__global__ __launch_bounds__(256) void hidden_k(
    const float* __restrict__ noise_t, const float* __restrict__ x,
    const float* __restrict__ rin_in, float* __restrict__ rin_out,
    unsigned char* __restrict__ in_spk,
    const float* __restrict__ W1T,
    float* __restrict__ v_h, float* __restrict__ r_h,
    unsigned char* __restrict__ hid_spk) {
  __shared__ unsigned short s_idx[IN];
  __shared__ int s_off[4];
  __shared__ int wsum[4];
  hidden_body(blockIdx.x, blockIdx.y, threadIdx.x, noise_t, x, rin_in, rin_out,
              in_spk, W1T, v_h, r_h, hid_spk, s_idx, s_off, wsum);
}

__global__ __launch_bounds__(256) void out_k(
    const unsigned char* __restrict__ hid_spk, const float* __restrict__ W2T,
    float* __restrict__ v_o, float* __restrict__ r_o, float* __restrict__ out_acc) {
  __shared__ unsigned short s_idx[HID];
  __shared__ int s_off[12];
  __shared__ int wsum[4];
  __shared__ float parts[11 * 256];
  out_body(blockIdx.x, blockIdx.y, threadIdx.x, hid_spk, W2T, v_o, r_o, out_acc,
           s_idx, s_off, wsum, parts);
}

// ---------------- merged step: out(t-1) || hidden(t) in one launch ---------------
// Roles are data-independent: out reads hid_spk_r (written last launch), hidden
// writes hid_spk_w (ping-pong). Shared memory is a union (max ~19.5 KB).
__global__ __launch_bounds__(256) void step_k(
    const float* __restrict__ noise_t, const float* __restrict__ x,
    const float* __restrict__ rin_in, float* __restrict__ rin_out,
    unsigned char* __restrict__ in_spk,
    const float* __restrict__ W1T,
    float* __restrict__ v_h, float* __restrict__ r_h,
    unsigned char* __restrict__ hid_spk_w,
    const unsigned char* __restrict__ hid_spk_r,
    const float* __restrict__ W2T,
    float* __restrict__ v_o, float* __restrict__ r_o, float* __restrict__ out_acc) {
  __shared__ __align__(16) unsigned char smem[19520];
  int b = blockIdx.y;
  if (blockIdx.x < 4) {
    unsigned short* s_idx = (unsigned short*)smem;              // 2048 B
    int* s_off = (int*)(smem + 2048);                            // 16 B
    int* wsum  = (int*)(smem + 2064);                            // 16 B
    hidden_body(blockIdx.x, b, threadIdx.x, noise_t, x, rin_in, rin_out,
                in_spk, W1T, v_h, r_h, hid_spk_w, s_idx, s_off, wsum);
  } else {
    unsigned short* s_idx = (unsigned short*)smem;              // 8192 B
    int* s_off = (int*)(smem + 8192);                            // 48 B
    int* wsum  = (int*)(smem + 8240);                            // 16 B
    float* parts = (float*)(smem + 8256);                        // 11264 B
    out_body(blockIdx.x - 4, b, threadIdx.x, hid_spk_r, W2T, v_o, r_o, out_acc,
             s_idx, s_off, wsum, parts);
  }
}

// ---------------- STDP stats, two-phase (t % 10 == 0) ----------------
// Phase 1: packed byte-lane partial sums over 16-row chunks (bytes are 0/1, totals
// <= 128: no cross-byte carry -> exact counts). atomicAdd targets distinct/thread.
#define NWSTAT ((IN + HID) / 4)   // 1280 u32 words
__global__ __launch_bounds__(256) void stats1_k(
    const unsigned char* __restrict__ in_spk, const unsigned char* __restrict__ hid_spk,
    unsigned* __restrict__ pcnt) {
  int w = blockIdx.x * 256 + threadIdx.x;   // word index in [0, NWSTAT)
  int r0 = blockIdx.y * 16;                 // 8 chunks x 16 rows
  unsigned s = 0;
  if (w < IN / 4) {
    const unsigned* p = (const unsigned*)in_spk;
    #pragma unroll
    for (int b = 0; b < 16; b++) s += p[(size_t)(r0 + b) * (IN / 4) + w];
  } else {
    const unsigned* p = (const unsigned*)hid_spk;
    int w2 = w - IN / 4;
    #pragma unroll
    for (int b = 0; b < 16; b++) s += p[(size_t)(r0 + b) * (HID / 4) + w2];
  }
  atomicAdd(pcnt + w, s);
}

// Phase 2: counts -> pm, trace updates, flags. Wave ballot + ONE atomic per wave.
__global__ __launch_bounds__(256) void stats2_k(
    const unsigned* __restrict__ pcnt,
    float* __restrict__ pre_m, float* __restrict__ post_m,
    float* __restrict__ tp, float* __restrict__ tn, int* __restrict__ flags) {
  int c = blockIdx.x * 256 + threadIdx.x;   // column in [0, IN+HID)
  int cnt = (int)((pcnt[c >> 2] >> ((c & 3) * 8)) & 0xff);
  int lane = threadIdx.x & 63;
  if (c < IN) {
    float pm = __fdiv_rn((float)cnt, 128.0f);       // exact (pow2)
    pre_m[c] = pm;
    tp[c] = __fadd_rn(__fmul_rn(0.9f, tp[c]), pm);  // tp_n committed (stdp step)
    unsigned long long any = __ballot(cnt > 0);
    if (any && lane == 0) atomicOr(flags + 0, 1);   // one atomic per wave
  } else {
    int h = c - IN;
    float pm = __fdiv_rn((float)cnt, 128.0f);
    post_m[h] = pm;
    tn[h] = __fadd_rn(__fmul_rn(0.9f, tn[h]), pm);
    unsigned long long any = __ballot(cnt > 0);
    if (any && lane == 0) atomicOr(flags + 1, 1);
  }
}

__global__ __launch_bounds__(256) void apply_k(
    float* __restrict__ W1T,
    const float* __restrict__ tp, const float* __restrict__ tn,
    const float* __restrict__ pre_m, const float* __restrict__ post_m,
    const int* __restrict__ flags) {
  if (!(flags[0] && flags[1])) return;   // 'both' gate
  size_t idx = (size_t)blockIdx.x * 256 + threadIdx.x;  // i*HID + h layout
  int i = (int)(idx >> 12);
  int h = (int)(idx & 4095);
  float a  = __fmul_rn(tp[i], post_m[h]);     // tp already == tp_n
  float b2 = __fmul_rn(pre_m[i], tn[h]);      // tn already == tn_n
  float d  = __fmul_rn(0.001f, __fsub_rn(a, b2));
  float w  = __fadd_rn(W1T[idx], d);
  w = fminf(fmaxf(w, -1.0f), 1.0f);           // jnp.clip: max then min
  W1T[idx] = w;
}

__global__ __launch_bounds__(256) void scale_k(const float* __restrict__ acc,
                                               float* __restrict__ out) {
  int j = blockIdx.x * 256 + threadIdx.x;
  out[j] = __fdiv_rn(acc[j], 100.0f);
}

// ---------------- host launcher ----------------
extern "C" void kernel_launch(void* const* d_in, const int* in_sizes, int n_in,
                              void* d_out, int out_size, void* d_ws, size_t ws_size,
                              hipStream_t stream) {
  (void)in_sizes; (void)n_in; (void)out_size; (void)ws_size;
  const float* x     = (const float*)d_in[0];
  const float* W1    = (const float*)d_in[1];
  const float* W2    = (const float*)d_in[2];
  const float* noise = (const float*)d_in[3];

  char* ws = (char*)d_ws;
  size_t off = 0;
  auto alloc = [&](size_t bytes) -> char* {
    char* p = ws + off;
    off += (bytes + 255) & ~(size_t)255;
    return p;
  };
  float* W1T   = (float*)alloc((size_t)IN * HID * 4);     // 16 MB working copy (i-major)
  float* W2T   = (float*)alloc((size_t)HID * OUTN * 4);   // 16 MB (h-major)
  float* v_h   = (float*)alloc((size_t)BB * HID * 4);
  float* r_h   = (float*)alloc((size_t)BB * HID * 4);
  float* v_o   = (float*)alloc((size_t)BB * OUTN * 4);
  float* r_o   = (float*)alloc((size_t)BB * OUTN * 4);
  float* rinA  = (float*)alloc((size_t)BB * IN * 4);      // ping-pong refractory state
  float* rinB  = (float*)alloc((size_t)BB * IN * 4);
  float* acc   = (float*)alloc((size_t)BB * OUTN * 4);
  float* tp    = (float*)alloc((size_t)IN * 4);
  float* tn    = (float*)alloc((size_t)HID * 4);
  float* pre_m = (float*)alloc((size_t)IN * 4);
  float* post_m= (float*)alloc((size_t)HID * 4);
  unsigned char* in_spk   = (unsigned char*)alloc((size_t)BB * IN);
  unsigned char* hid_spkA = (unsigned char*)alloc((size_t)BB * HID);  // ping-pong
  unsigned char* hid_spkB = (unsigned char*)alloc((size_t)BB * HID);
  unsigned* pcnt = (unsigned*)alloc((size_t)10 * NWSTAT * 4);  // per-STDP-step slots
  int* flags   = (int*)alloc(2 * 10 * sizeof(int));            // per-STDP-step slots

  // zero all state (ws is poisoned before every call)
  hipMemsetAsync(v_h, 0, (size_t)BB * HID * 4, stream);
  hipMemsetAsync(r_h, 0, (size_t)BB * HID * 4, stream);
  hipMemsetAsync(v_o, 0, (size_t)BB * OUTN * 4, stream);
  hipMemsetAsync(r_o, 0, (size_t)BB * OUTN * 4, stream);
  hipMemsetAsync(rinA, 0, (size_t)BB * IN * 4, stream);
  hipMemsetAsync(acc, 0, (size_t)BB * OUTN * 4, stream);
  hipMemsetAsync(tp,  0, (size_t)IN * 4, stream);
  hipMemsetAsync(tn,  0, (size_t)HID * 4, stream);
  hipMemsetAsync(pcnt, 0, (size_t)10 * NWSTAT * 4, stream);
  hipMemsetAsync(flags, 0, 2 * 10 * sizeof(int), stream);

  // W1 (HID x IN) -> W1T (IN x HID); W2 (OUTN x HID) -> W2T (HID x OUTN). Tiled.
  ttrans_k<<<dim3(IN / 32, HID / 32), 256, 0, stream>>>(W1, W1T, HID, IN);
  ttrans_k<<<dim3(HID / 32, OUTN / 32), 256, 0, stream>>>(W2, W2T, OUTN, HID);

  float* rin_in = rinA;
  float* rin_out = rinB;

  // t = 0: hidden only
  hidden_k<<<dim3(HID / 1024, BB), 256, 0, stream>>>(noise, x, rin_in, rin_out, in_spk,
                                                     W1T, v_h, r_h, hid_spkA);
  {
    unsigned* pc = pcnt;  int* fl = flags;
    stats1_k<<<dim3(NWSTAT / 256, 8), 256, 0, stream>>>(in_spk, hid_spkA, pc);
    stats2_k<<<(IN + HID) / 256, 256, 0, stream>>>(pc, pre_m, post_m, tp, tn, fl);
    apply_k<<<(IN * HID) / 256, 256, 0, stream>>>(W1T, tp, tn, pre_m, post_m, fl);
  }
  { float* tmpp = rin_in; rin_in = rin_out; rin_out = tmpp; }

  // t = 1..99: merged out(t-1) || hidden(t)
  for (int t = 1; t < TSTEPS; t++) {
    const float* nz = noise + (size_t)t * BB * IN;
    unsigned char* hs_w = (t & 1) ? hid_spkB : hid_spkA;
    unsigned char* hs_r = (t & 1) ? hid_spkA : hid_spkB;
    step_k<<<dim3(8, BB), 256, 0, stream>>>(nz, x, rin_in, rin_out, in_spk,
                                            W1T, v_h, r_h, hs_w, hs_r,
                                            W2T, v_o, r_o, acc);
    if (t % 10 == 0) {
      unsigned* pc = pcnt + (size_t)NWSTAT * (t / 10);
      int* fl = flags + 2 * (t / 10);
      stats1_k<<<dim3(NWSTAT / 256, 8), 256, 0, stream>>>(in_spk, hs_w, pc);
      stats2_k<<<(IN + HID) / 256, 256, 0, stream>>>(pc, pre_m, post_m, tp, tn, fl);
      apply_k<<<(IN * HID) / 256, 256, 0, stream>>>(W1T, tp, tn, pre_m, post_m, fl);
    }
    float* tmpp = rin_in; rin_in = rin_out; rin_out = tmpp;
  }

  // final: out(99)
  unsigned char* hs_last = ((TSTEPS - 1) & 1) ? hid_spkB : hid_spkA;
  out_k<<<dim3(OUTN / 256, BB), 256, 0, stream>>>(hs_last, W2T, v_o, r_o, acc);

  scale_k<<<(BB * OUTN) / 256, 256, 0, stream>>>(acc, (float*)d_out);
}

// Round 9
// 1487.370 us; speedup vs baseline: 3.2230x; 1.0090x over previous
//
#include <hip/hip_runtime.h>
#include <cstdint>
#include <cstddef>

#define BB   128
#define IN   1024
#define HID  4096
#define OUTN 1024
#define TSTEPS 100
#define KC   384   // OpenBLAS SGEMM_DEFAULT_Q — panel structure must be preserved exactly

// ---------------- tiled transpose: dst[c*R + r] = src[r*C + c] ----------------
__global__ __launch_bounds__(256) void ttrans_k(const float* __restrict__ src,
                                                float* __restrict__ dst,
                                                int R, int C) {
  __shared__ float tile[32][33];
  int tx = threadIdx.x & 31;
  int ty = threadIdx.x >> 5;            // 0..7
  int c0 = blockIdx.x * 32, r0 = blockIdx.y * 32;
  #pragma unroll
  for (int j = 0; j < 32; j += 8)
    tile[ty + j][tx] = src[(size_t)(r0 + ty + j) * C + (c0 + tx)];
  __syncthreads();
  #pragma unroll
  for (int j = 0; j < 32; j += 8)
    dst[(size_t)(c0 + ty + j) * R + (r0 + tx)] = tile[tx][ty + j];
}

// f32 LIF exactly mirroring the reference op order (no FMA contraction).
__device__ __forceinline__ unsigned char lif_f32(float I, float& v, float& r) {
  bool active = I > 0.0f;
  bool refrac = r > 0.0f;
  float vi = __fadd_rn(__fmul_rn(v, 0.95f), I);
  bool fired = active && !refrac && (vi >= 1.0f);
  float vn = !active ? v : ((refrac || fired) ? 0.0f : vi);
  float rn = !active ? r : (refrac ? (r - 1.0f) : (fired ? 2.0f : r));
  v = vn; r = rn;
  return fired ? (unsigned char)1 : (unsigned char)0;
}

// 8-deep batched gather over [ks,ke): 8 float4 loads in flight, ordered adds per
// column (ascending k) — bit-identical to the sequential gated scan.
#define GATHER8(SH)                                                              \
  {                                                                              \
    int k = ks;                                                                  \
    for (; k + 8 <= ke; k += 8) {                                                \
      unsigned o0 = ((unsigned)s_idx[k]     << SH) + cb;                         \
      unsigned o1 = ((unsigned)s_idx[k + 1] << SH) + cb;                         \
      unsigned o2 = ((unsigned)s_idx[k + 2] << SH) + cb;                         \
      unsigned o3 = ((unsigned)s_idx[k + 3] << SH) + cb;                         \
      unsigned o4 = ((unsigned)s_idx[k + 4] << SH) + cb;                         \
      unsigned o5 = ((unsigned)s_idx[k + 5] << SH) + cb;                         \
      unsigned o6 = ((unsigned)s_idx[k + 6] << SH) + cb;                         \
      unsigned o7 = ((unsigned)s_idx[k + 7] << SH) + cb;                         \
      float4 w0 = *reinterpret_cast<const float4*>(Wb + o0);                     \
      float4 w1 = *reinterpret_cast<const float4*>(Wb + o1);                     \
      float4 w2 = *reinterpret_cast<const float4*>(Wb + o2);                     \
      float4 w3 = *reinterpret_cast<const float4*>(Wb + o3);                     \
      float4 w4 = *reinterpret_cast<const float4*>(Wb + o4);                     \
      float4 w5 = *reinterpret_cast<const float4*>(Wb + o5);                     \
      float4 w6 = *reinterpret_cast<const float4*>(Wb + o6);                     \
      float4 w7 = *reinterpret_cast<const float4*>(Wb + o7);                     \
      a0 = __fadd_rn(a0, w0.x); a1 = __fadd_rn(a1, w0.y);                        \
      a2 = __fadd_rn(a2, w0.z); a3 = __fadd_rn(a3, w0.w);                        \
      a0 = __fadd_rn(a0, w1.x); a1 = __fadd_rn(a1, w1.y);                        \
      a2 = __fadd_rn(a2, w1.z); a3 = __fadd_rn(a3, w1.w);                        \
      a0 = __fadd_rn(a0, w2.x); a1 = __fadd_rn(a1, w2.y);                        \
      a2 = __fadd_rn(a2, w2.z); a3 = __fadd_rn(a3, w2.w);                        \
      a0 = __fadd_rn(a0, w3.x); a1 = __fadd_rn(a1, w3.y);                        \
      a2 = __fadd_rn(a2, w3.z); a3 = __fadd_rn(a3, w3.w);                        \
      a0 = __fadd_rn(a0, w4.x); a1 = __fadd_rn(a1, w4.y);                        \
      a2 = __fadd_rn(a2, w4.z); a3 = __fadd_rn(a3, w4.w);                        \
      a0 = __fadd_rn(a0, w5.x); a1 = __fadd_rn(a1, w5.y);                        \
      a2 = __fadd_rn(a2, w5.z); a3 = __fadd_rn(a3, w5.w);                        \
      a0 = __fadd_rn(a0, w6.x); a1 = __fadd_rn(a1, w6.y);                        \
      a2 = __fadd_rn(a2, w6.z); a3 = __fadd_rn(a3, w6.w);                        \
      a0 = __fadd_rn(a0, w7.x); a1 = __fadd_rn(a1, w7.y);                        \
      a2 = __fadd_rn(a2, w7.z); a3 = __fadd_rn(a3, w7.w);                        \
    }                                                                            \
    if (k + 4 <= ke) {                                                           \
      unsigned o0 = ((unsigned)s_idx[k]     << SH) + cb;                         \
      unsigned o1 = ((unsigned)s_idx[k + 1] << SH) + cb;                         \
      unsigned o2 = ((unsigned)s_idx[k + 2] << SH) + cb;                         \
      unsigned o3 = ((unsigned)s_idx[k + 3] << SH) + cb;                         \
      float4 w0 = *reinterpret_cast<const float4*>(Wb + o0);                     \
      float4 w1 = *reinterpret_cast<const float4*>(Wb + o1);                     \
      float4 w2 = *reinterpret_cast<const float4*>(Wb + o2);                     \
      float4 w3 = *reinterpret_cast<const float4*>(Wb + o3);                     \
      a0 = __fadd_rn(a0, w0.x); a1 = __fadd_rn(a1, w0.y);                        \
      a2 = __fadd_rn(a2, w0.z); a3 = __fadd_rn(a3, w0.w);                        \
      a0 = __fadd_rn(a0, w1.x); a1 = __fadd_rn(a1, w1.y);                        \
      a2 = __fadd_rn(a2, w1.z); a3 = __fadd_rn(a3, w1.w);                        \
      a0 = __fadd_rn(a0, w2.x); a1 = __fadd_rn(a1, w2.y);                        \
      a2 = __fadd_rn(a2, w2.z); a3 = __fadd_rn(a3, w2.w);                        \
      a0 = __fadd_rn(a0, w3.x); a1 = __fadd_rn(a1, w3.y);                        \
      a2 = __fadd_rn(a2, w3.z); a3 = __fadd_rn(a3, w3.w);                        \
      k += 4;                                                                    \
    }                                                                            \
    for (; k < ke; k++) {                                                        \
      unsigned oo = ((unsigned)s_idx[k] << SH) + cb;                             \
      float4 w = *reinterpret_cast<const float4*>(Wb + oo);                      \
      a0 = __fadd_rn(a0, w.x); a1 = __fadd_rn(a1, w.y);                          \
      a2 = __fadd_rn(a2, w.z); a3 = __fadd_rn(a3, w.w);                          \
    }                                                                            \
  }

// ================= hidden role: fused encode + compaction + sparse panel sum =====
__device__ __forceinline__ void hidden_body(
    int bx, int b, int tid,
    const float* __restrict__ noise_t, const float* __restrict__ x,
    const float* __restrict__ rin_in, float* __restrict__ rin_out,
    unsigned char* __restrict__ in_spk,
    const float* __restrict__ W1T,
    float* __restrict__ v_h, float* __restrict__ r_h,
    unsigned char* __restrict__ hid_spk,
    unsigned short* s_idx, int* s_off, int* wsum) {
  // ---- fused encode: each thread owns k in [tid*4, tid*4+4) ----
  size_t ebase = (size_t)b * IN + (size_t)tid * 4;
  const float4 xv = *reinterpret_cast<const float4*>(x + ebase);
  const float4 nv = *reinterpret_cast<const float4*>(noise_t + ebase);
  const float4 rv = *reinterpret_cast<const float4*>(rin_in + ebase);
  float px[4] = {xv.x, xv.y, xv.z, xv.w};
  float pn[4] = {nv.x, nv.y, nv.z, nv.w};
  float pr[4] = {rv.x, rv.y, rv.z, rv.w};
  int f[4]; float rn[4];
  #pragma unroll
  for (int j = 0; j < 4; j++) {
    float p = __fmul_rn(px[j], 100.0f);
    p = fminf(fmaxf(p, 0.0f), 100.0f);
    p = __fmul_rn(p, 0.001f);
    bool s = pn[j] < p;                  // Bernoulli encode (strict <)
    bool refrac = pr[j] > 0.0f;
    bool fired = s && !refrac;           // input-layer v == 0 always (proven)
    rn[j] = !s ? pr[j] : (refrac ? (pr[j] - 1.0f) : 2.0f);
    f[j] = fired ? 1 : 0;
  }
  if (bx == 0) {                         // single owner commits state
    *reinterpret_cast<float4*>(rin_out + ebase) = make_float4(rn[0], rn[1], rn[2], rn[3]);
    uchar4 sp; sp.x = (unsigned char)f[0]; sp.y = (unsigned char)f[1];
    sp.z = (unsigned char)f[2]; sp.w = (unsigned char)f[3];
    *reinterpret_cast<uchar4*>(in_spk + ebase) = sp;
  }
  int cnt = f[0] + f[1] + f[2] + f[3];

  // ---- block exclusive scan ----
  int lane = tid & 63, wv = tid >> 6;
  int inc = cnt;
  #pragma unroll
  for (int d = 1; d < 64; d <<= 1) {
    int nn = __shfl_up(inc, d, 64);
    if (lane >= d) inc += nn;
  }
  if (lane == 63) wsum[wv] = inc;
  __syncthreads();
  int wbase = 0;
  #pragma unroll
  for (int w = 0; w < 4; w++) if (w < wv) wbase += wsum[w];
  int excl = wbase + inc - cnt;

  int o = excl, kb = tid * 4;
  if (f[0]) s_idx[o++] = (unsigned short)(kb);
  if (f[1]) s_idx[o++] = (unsigned short)(kb + 1);
  if (f[2]) s_idx[o++] = (unsigned short)(kb + 2);
  if (f[3]) s_idx[o++] = (unsigned short)(kb + 3);
  if (tid == 0)   s_off[0] = 0;
  if (tid == 96)  s_off[1] = excl;       // panel k=384
  if (tid == 192) s_off[2] = excl;       // panel k=768
  if (tid == 255) s_off[3] = excl + cnt;
  __syncthreads();

  // ---- gather: thread owns h0..h0+3; 32-bit offsets from uniform base ----
  int h0 = bx * 1024 + tid * 4;
  const char* Wb = (const char*)W1T;
  unsigned cb = (unsigned)h0 << 2;
  float t0 = 0.0f, t1 = 0.0f, t2 = 0.0f, t3 = 0.0f;
  #pragma unroll
  for (int p = 0; p < 3; p++) {
    int ks = s_off[p], ke = s_off[p + 1];
    float a0 = 0.0f, a1 = 0.0f, a2 = 0.0f, a3 = 0.0f;
    GATHER8(14)                          // k*HID*4
    t0 = __fadd_rn(t0, a0); t1 = __fadd_rn(t1, a1);   // rn(0+P0)=P0 exact
    t2 = __fadd_rn(t2, a2); t3 = __fadd_rn(t3, a3);
  }
  size_t idx = (size_t)b * HID + h0;
  float4 vv = *reinterpret_cast<float4*>(v_h + idx);
  float4 rr = *reinterpret_cast<float4*>(r_h + idx);
  uchar4 sp;
  sp.x = lif_f32(t0, vv.x, rr.x);
  sp.y = lif_f32(t1, vv.y, rr.y);
  sp.z = lif_f32(t2, vv.z, rr.z);
  sp.w = lif_f32(t3, vv.w, rr.w);
  *reinterpret_cast<float4*>(v_h + idx) = vv;
  *reinterpret_cast<float4*>(r_h + idx) = rr;
  *reinterpret_cast<uchar4*>(hid_spk + idx) = sp;
}

// ================= out role: wave-split panels, 4 cols/thread, fold + LIF ========
__device__ __forceinline__ void out_body(
    int bx, int b, int tid,
    const unsigned char* __restrict__ hid_spk,
    const float* __restrict__ W2T,
    float* __restrict__ v_o, float* __restrict__ r_o,
    float* __restrict__ out_acc,
    unsigned short* s_idx, int* s_off, int* wsum, float* parts) {
  int lane = tid & 63, kg = tid >> 6;

  // each thread owns k in [tid*16, tid*16+16)
  uint4 u = *reinterpret_cast<const uint4*>(hid_spk + (size_t)b * HID + tid * 16);
  unsigned ww[4] = {u.x, u.y, u.z, u.w};
  int cnt = 0;
  #pragma unroll
  for (int j = 0; j < 16; j++) cnt += (ww[j >> 2] >> ((j & 3) * 8)) & 0xff;

  int inc = cnt;
  #pragma unroll
  for (int d = 1; d < 64; d <<= 1) {
    int nn = __shfl_up(inc, d, 64);
    if (lane >= d) inc += nn;
  }
  if (lane == 63) wsum[kg] = inc;
  __syncthreads();
  int wbase = 0;
  #pragma unroll
  for (int w = 0; w < 4; w++) if (w < kg) wbase += wsum[w];
  int excl = wbase + inc - cnt;

  int oo = excl, kb = tid * 16;
  #pragma unroll
  for (int j = 0; j < 16; j++) {
    if ((ww[j >> 2] >> ((j & 3) * 8)) & 0xff) s_idx[oo++] = (unsigned short)(kb + j);
  }
  // panel p starts at k = 384*p -> thread 24*p (384/16 == 24, exact)
  if ((tid % 24) == 0 && tid <= 240) s_off[tid / 24] = excl;
  if (tid == 255) s_off[11] = excl + cnt;
  __syncthreads();

  // ---- wave kg computes its panels for cols [bx*256 + lane*4 .. +4) ----
  const int pstart = (kg == 0) ? 0 : (kg == 1) ? 3 : (kg == 2) ? 6 : 9;
  const int pend   = (kg == 0) ? 3 : (kg == 1) ? 6 : (kg == 2) ? 9 : 11;
  int col0 = lane * 4;
  const char* Wb = (const char*)W2T;
  unsigned cb = ((unsigned)(bx * 256 + col0)) << 2;
  for (int p = pstart; p < pend; p++) {
    int ks = s_off[p], ke = s_off[p + 1];
    float a0 = 0.0f, a1 = 0.0f, a2 = 0.0f, a3 = 0.0f;
    GATHER8(12)                          // k*OUTN*4
    *reinterpret_cast<float4*>(parts + p * 256 + col0) = make_float4(a0, a1, a2, a3);
  }
  __syncthreads();

  // ---- each thread folds one column (ordered 11-add left-fold) + LIF ----
  float total = 0.0f;
  #pragma unroll
  for (int p = 0; p < 11; p++) total = __fadd_rn(total, parts[p * 256 + tid]);
  int o = bx * 256 + tid;
  size_t idx = (size_t)b * OUTN + o;
  float v = v_o[idx], r = r_o[idx];
  unsigned char fired = lif_f32(total, v, r);
  v_o[idx] = v; r_o[idx] = r;
  if (fired) out_acc[idx] = __fadd_rn(out_acc[idx], 1.0f);  // exact int count
}

// ---------------- standalone boundary kernels ----------------
__global__ __launch_bounds__(256) void hidden_k(
    const float* __restrict__ noise_t, const float* __restrict__ x,
    const float* __restrict__ rin_in, float* __restrict__ rin_out,
    unsigned char* __restrict__ in_spk,
    const float* __restrict__ W1T,
    float* __restrict__ v_h, float* __restrict__ r_h,
    unsigned char* __restrict__ hid_spk) {
  __shared__ unsigned short s_idx[IN];
  __shared__ int s_off[4];
  __shared__ int wsum[4];
  hidden_body(blockIdx.x, blockIdx.y, threadIdx.x, noise_t, x, rin_in, rin_out,
              in_spk, W1T, v_h, r_h, hid_spk, s_idx, s_off, wsum);
}

__global__ __launch_bounds__(256) void out_k(
    const unsigned char* __restrict__ hid_spk, const float* __restrict__ W2T,
    float* __restrict__ v_o, float* __restrict__ r_o, float* __restrict__ out_acc) {
  __shared__ unsigned short s_idx[HID];
  __shared__ int s_off[12];
  __shared__ int wsum[4];
  __shared__ float parts[11 * 256];
  out_body(blockIdx.x, blockIdx.y, threadIdx.x, hid_spk, W2T, v_o, r_o, out_acc,
           s_idx, s_off, wsum, parts);
}

// ---------------- merged step: out(t-1) || hidden(t) in one launch ---------------
__global__ __launch_bounds__(256) void step_k(
    const float* __restrict__ noise_t, const float* __restrict__ x,
    const float* __restrict__ rin_in, float* __restrict__ rin_out,
    unsigned char* __restrict__ in_spk,
    const float* __restrict__ W1T,
    float* __restrict__ v_h, float* __restrict__ r_h,
    unsigned char* __restrict__ hid_spk_w,
    const unsigned char* __restrict__ hid_spk_r,
    const float* __restrict__ W2T,
    float* __restrict__ v_o, float* __restrict__ r_o, float* __restrict__ out_acc) {
  __shared__ __align__(16) unsigned char smem[19520];
  int b = blockIdx.y;
  if (blockIdx.x < 4) {
    unsigned short* s_idx = (unsigned short*)smem;
    int* s_off = (int*)(smem + 2048);
    int* wsum  = (int*)(smem + 2064);
    hidden_body(blockIdx.x, b, threadIdx.x, noise_t, x, rin_in, rin_out,
                in_spk, W1T, v_h, r_h, hid_spk_w, s_idx, s_off, wsum);
  } else {
    unsigned short* s_idx = (unsigned short*)smem;
    int* s_off = (int*)(smem + 8192);
    int* wsum  = (int*)(smem + 8240);
    float* parts = (float*)(smem + 8256);
    out_body(blockIdx.x - 4, b, threadIdx.x, hid_spk_r, W2T, v_o, r_o, out_acc,
             s_idx, s_off, wsum, parts);
  }
}

// ---------------- STDP: stats1 (counts + flags) then apply2 (trace + W) ----------
// stats1: packed byte-lane partial sums over 8-row chunks (bytes 0/1, totals <=128
// per byte -> packed u32 atomicAdd exact). Flags via one ballot-atomicOr per wave.
#define NWSTAT ((IN + HID) / 4)   // 1280 u32 words
__global__ __launch_bounds__(256) void stats1_k(
    const unsigned char* __restrict__ in_spk, const unsigned char* __restrict__ hid_spk,
    unsigned* __restrict__ pcnt, int* __restrict__ flags) {
  int w = blockIdx.x * 256 + threadIdx.x;   // word index in [0, NWSTAT)
  int r0 = blockIdx.y * 8;                  // 16 chunks x 8 rows
  int lane = threadIdx.x & 63;
  unsigned s = 0;
  if (w < IN / 4) {
    const unsigned* p = (const unsigned*)in_spk;
    #pragma unroll
    for (int b = 0; b < 8; b++) s += p[(size_t)(r0 + b) * (IN / 4) + w];
    atomicAdd(pcnt + w, s);
    unsigned long long any = __ballot(s > 0);
    if (any && lane == 0) atomicOr(flags + 0, 1);
  } else {
    const unsigned* p = (const unsigned*)hid_spk;
    int w2 = w - IN / 4;
    #pragma unroll
    for (int b = 0; b < 8; b++) s += p[(size_t)(r0 + b) * (HID / 4) + w2];
    atomicAdd(pcnt + w, s);
    unsigned long long any = __ballot(s > 0);
    if (any && lane == 0) atomicOr(flags + 1, 1);
  }
}

// apply2: pm = cnt * 2^-7 (== __fdiv_rn(cnt,128): both correctly rounded, pow2).
// tp/tn ping-pong: all threads READ tp_in/tn_in (never written here) -> race-free;
// designated threads COMMIT tp_out/tn_out unconditionally (reference commits the
// traces on every stdp step); W1T update gated by 'both' flags.
__global__ __launch_bounds__(256) void apply2_k(
    float* __restrict__ W1T,
    const unsigned* __restrict__ pcnt,
    const float* __restrict__ tp_in, float* __restrict__ tp_out,
    const float* __restrict__ tn_in, float* __restrict__ tn_out,
    const int* __restrict__ flags) {
  size_t idx = (size_t)blockIdx.x * 256 + threadIdx.x;  // i*HID + h layout
  int i = (int)(idx >> 12);
  int h = (int)(idx & 4095);
  int cnt_i = (int)((pcnt[i >> 2] >> ((i & 3) * 8)) & 0xff);
  int ch = IN + h;
  int cnt_h = (int)((pcnt[ch >> 2] >> ((ch & 3) * 8)) & 0xff);
  float pm_i = __fmul_rn((float)cnt_i, 0.0078125f);     // == fdiv_rn(cnt,128)
  float pm_h = __fmul_rn((float)cnt_h, 0.0078125f);
  float tpn = __fadd_rn(__fmul_rn(0.9f, tp_in[i]), pm_i);
  float tnn = __fadd_rn(__fmul_rn(0.9f, tn_in[h]), pm_h);
  if (h == 0) tp_out[i] = tpn;           // one committer per i
  if (i == 0) tn_out[h] = tnn;           // one committer per h
  if (!(flags[0] && flags[1])) return;   // 'both' gate (W only)
  float a  = __fmul_rn(tpn, pm_h);       // tp_n * post_m
  float b2 = __fmul_rn(pm_i, tnn);       // pre_m * tn_n
  float d  = __fmul_rn(0.001f, __fsub_rn(a, b2));
  float w  = __fadd_rn(W1T[idx], d);
  w = fminf(fmaxf(w, -1.0f), 1.0f);      // jnp.clip: max then min
  W1T[idx] = w;
}

__global__ __launch_bounds__(256) void scale_k(const float* __restrict__ acc,
                                               float* __restrict__ out) {
  int j = blockIdx.x * 256 + threadIdx.x;
  out[j] = __fdiv_rn(acc[j], 100.0f);
}

// ---------------- host launcher ----------------
extern "C" void kernel_launch(void* const* d_in, const int* in_sizes, int n_in,
                              void* d_out, int out_size, void* d_ws, size_t ws_size,
                              hipStream_t stream) {
  (void)in_sizes; (void)n_in; (void)out_size; (void)ws_size;
  const float* x     = (const float*)d_in[0];
  const float* W1    = (const float*)d_in[1];
  const float* W2    = (const float*)d_in[2];
  const float* noise = (const float*)d_in[3];

  char* ws = (char*)d_ws;
  size_t off = 0;
  auto alloc = [&](size_t bytes) -> char* {
    char* p = ws + off;
    off += (bytes + 255) & ~(size_t)255;
    return p;
  };
  float* W1T   = (float*)alloc((size_t)IN * HID * 4);     // 16 MB working copy (i-major)
  float* W2T   = (float*)alloc((size_t)HID * OUTN * 4);   // 16 MB (h-major)
  float* v_h   = (float*)alloc((size_t)BB * HID * 4);
  float* r_h   = (float*)alloc((size_t)BB * HID * 4);
  float* v_o   = (float*)alloc((size_t)BB * OUTN * 4);
  float* r_o   = (float*)alloc((size_t)BB * OUTN * 4);
  float* rinA  = (float*)alloc((size_t)BB * IN * 4);      // ping-pong refractory state
  float* rinB  = (float*)alloc((size_t)BB * IN * 4);
  float* acc   = (float*)alloc((size_t)BB * OUTN * 4);
  float* tpA   = (float*)alloc((size_t)IN * 4);           // ping-pong traces
  float* tpB   = (float*)alloc((size_t)IN * 4);
  float* tnA   = (float*)alloc((size_t)HID * 4);
  float* tnB   = (float*)alloc((size_t)HID * 4);
  unsigned char* in_spk   = (unsigned char*)alloc((size_t)BB * IN);
  unsigned char* hid_spkA = (unsigned char*)alloc((size_t)BB * HID);  // ping-pong
  unsigned char* hid_spkB = (unsigned char*)alloc((size_t)BB * HID);
  unsigned* pcnt = (unsigned*)alloc((size_t)10 * NWSTAT * 4);  // per-STDP-step slots
  int* flags   = (int*)alloc(2 * 10 * sizeof(int));            // per-STDP-step slots

  // zero all state (ws is poisoned before every call)
  hipMemsetAsync(v_h, 0, (size_t)BB * HID * 4, stream);
  hipMemsetAsync(r_h, 0, (size_t)BB * HID * 4, stream);
  hipMemsetAsync(v_o, 0, (size_t)BB * OUTN * 4, stream);
  hipMemsetAsync(r_o, 0, (size_t)BB * OUTN * 4, stream);
  hipMemsetAsync(rinA, 0, (size_t)BB * IN * 4, stream);
  hipMemsetAsync(acc, 0, (size_t)BB * OUTN * 4, stream);
  hipMemsetAsync(tpA, 0, (size_t)IN * 4, stream);
  hipMemsetAsync(tnA, 0, (size_t)HID * 4, stream);
  hipMemsetAsync(pcnt, 0, (size_t)10 * NWSTAT * 4, stream);
  hipMemsetAsync(flags, 0, 2 * 10 * sizeof(int), stream);

  // W1 (HID x IN) -> W1T (IN x HID); W2 (OUTN x HID) -> W2T (HID x OUTN). Tiled.
  ttrans_k<<<dim3(IN / 32, HID / 32), 256, 0, stream>>>(W1, W1T, HID, IN);
  ttrans_k<<<dim3(HID / 32, OUTN / 32), 256, 0, stream>>>(W2, W2T, OUTN, HID);

  float* rin_in = rinA;
  float* rin_out = rinB;
  float* tp_in = tpA; float* tp_out = tpB;
  float* tn_in = tnA; float* tn_out = tnB;

  // t = 0: hidden only
  hidden_k<<<dim3(HID / 1024, BB), 256, 0, stream>>>(noise, x, rin_in, rin_out, in_spk,
                                                     W1T, v_h, r_h, hid_spkA);
  {
    unsigned* pc = pcnt;  int* fl = flags;
    stats1_k<<<dim3(NWSTAT / 256, 16), 256, 0, stream>>>(in_spk, hid_spkA, pc, fl);
    apply2_k<<<(IN * HID) / 256, 256, 0, stream>>>(W1T, pc, tp_in, tp_out,
                                                   tn_in, tn_out, fl);
    float* t1 = tp_in; tp_in = tp_out; tp_out = t1;
    float* t2 = tn_in; tn_in = tn_out; tn_out = t2;
  }
  { float* tmpp = rin_in; rin_in = rin_out; rin_out = tmpp; }

  // t = 1..99: merged out(t-1) || hidden(t)
  for (int t = 1; t < TSTEPS; t++) {
    const float* nz = noise + (size_t)t * BB * IN;
    unsigned char* hs_w = (t & 1) ? hid_spkB : hid_spkA;
    unsigned char* hs_r = (t & 1) ? hid_spkA : hid_spkB;
    step_k<<<dim3(8, BB), 256, 0, stream>>>(nz, x, rin_in, rin_out, in_spk,
                                            W1T, v_h, r_h, hs_w, hs_r,
                                            W2T, v_o, r_o, acc);
    if (t % 10 == 0) {
      unsigned* pc = pcnt + (size_t)NWSTAT * (t / 10);
      int* fl = flags + 2 * (t / 10);
      stats1_k<<<dim3(NWSTAT / 256, 16), 256, 0, stream>>>(in_spk, hs_w, pc, fl);
      apply2_k<<<(IN * HID) / 256, 256, 0, stream>>>(W1T, pc, tp_in, tp_out,
                                                     tn_in, tn_out, fl);
      float* t1 = tp_in; tp_in = tp_out; tp_out = t1;
      float* t2 = tn_in; tn_in = tn_out; tn_out = t2;
    }
    float* tmpp = rin_in; rin_in = rin_out; rin_out = tmpp;
  }

  // final: out(99)
  unsigned char* hs_last = ((TSTEPS - 1) & 1) ? hid_spkB : hid_spkA;
  out_k<<<dim3(OUTN / 256, BB), 256, 0, stream>>>(hs_last, W2T, v_o, r_o, acc);

  scale_k<<<(BB * OUTN) / 256, 256, 0, stream>>>(acc, (float*)d_out);
}